// Round 1
// baseline (1474.536 us; speedup 1.0000x reference)
//
#include <hip/hip_runtime.h>
#include <math.h>

#define NEG 0.01f
__device__ __forceinline__ float lrelu(float v){ return v > 0.f ? v : NEG*v; }
__device__ __forceinline__ float frelu(float v){ return v > 0.f ? v : 0.f; }

// ================= K1: fused conv stack (3x conv+bn+relu+pool) + map2 =================
// one block per signal (4096 signals), 256 threads
// LDS layout (floats): p1Tp @0 [64][76]; p2Tp @4864 [128][44]; sigp @10496 [144];
//                      wst @10640 [4224]; aflat @14864 [576]   total 15440 f = 61760 B
__global__ __launch_bounds__(256) void k_conv(
    const float* __restrict__ xenc,
    const float* __restrict__ w1, const float* __restrict__ g1, const float* __restrict__ b1,
    const float* __restrict__ w2, const float* __restrict__ g2, const float* __restrict__ b2,
    const float* __restrict__ w3, const float* __restrict__ g3, const float* __restrict__ b3,
    const float* __restrict__ m2w, const float* __restrict__ m2b,
    const float* __restrict__ m2g, const float* __restrict__ m2bb,
    float* __restrict__ a2)
{
    __shared__ __align__(16) float sm[15440];
    const int t = threadIdx.x;
    const int s = blockIdx.x;

    for (int i = t; i < 10640; i += 256) sm[i] = 0.f;
    __syncthreads();
    if (t < 128) sm[10496 + 4 + t] = xenc[(size_t)s*128 + t];
    sm[10640 + t]       = w1[t];
    sm[10640 + 256 + t] = w1[256 + t];
    __syncthreads();

    // ---- conv1 + pool -> p1Tp[o][q+5], o<64, q<65 (sigp[x] = sig[x-4], zero-padded)
    {
        const int o = t & 63, qq = t >> 6;
        float w1r[8];
        #pragma unroll
        for (int k = 0; k < 8; ++k) w1r[k] = sm[10640 + o*8 + k];
        const float g = g1[o], b = b1[o];
        for (int m = 0; m < 17; ++m) {
            int q = qq + 4*m;
            if (q < 65) {
                float s0 = 0.f, s1 = 0.f;
                #pragma unroll
                for (int k = 0; k < 8; ++k) {             // conv at p reads sigp[p+k]
                    s0 += sm[10496 + (2*q - 1) + k] * w1r[k];
                    s1 += sm[10496 + (2*q)     + k] * w1r[k];
                }
                float v = frelu(s1*g + b);
                if (q > 0) v = fmaxf(v, frelu(s0*g + b));
                sm[o*76 + q + 5] = v;
            }
        }
    }
    __syncthreads();

    // ---- conv2 + pool -> p2Tp[o][q+5], o<128, q<34 ; K=(64c x 8k), c-chunks of 4
    {
        const int o4 = t & 31, qq = t >> 5;    // o = o4*4+oo ; qq in [0,8)
        float acc[5][2][4];
        #pragma unroll
        for (int m=0;m<5;++m){ acc[m][0][0]=acc[m][0][1]=acc[m][0][2]=acc[m][0][3]=0.f;
                               acc[m][1][0]=acc[m][1][1]=acc[m][1][2]=acc[m][1][3]=0.f; }
        int p0m[5];
        #pragma unroll
        for (int m=0;m<5;++m){ int q = qq + 8*m; if (q>33) q=33; p0m[m] = 2*q-1; }
        for (int cc = 0; cc < 16; ++cc) {
            __syncthreads();
            #pragma unroll
            for (int r = 0; r < 16; ++r) {       // stage w2 chunk: [ck][132] o-minor
                int j = r*256 + t;
                int o = j >> 5, ck = j & 31;
                sm[10640 + ck*132 + o] = w2[o*512 + cc*32 + ck];
            }
            __syncthreads();
            for (int ck = 0; ck < 32; ++ck) {
                float4 w4 = *(const float4*)&sm[10640 + ck*132 + o4*4];
                int c = cc*4 + (ck>>3), k = ck & 7;
                const float* pc = &sm[c*76 + k + 1];      // pc[p] = input at conv-pos p
                #pragma unroll
                for (int m=0;m<5;++m){
                    float pv0 = pc[p0m[m]];
                    float pv1 = pc[p0m[m]+1];
                    acc[m][0][0] += pv0*w4.x; acc[m][0][1] += pv0*w4.y;
                    acc[m][0][2] += pv0*w4.z; acc[m][0][3] += pv0*w4.w;
                    acc[m][1][0] += pv1*w4.x; acc[m][1][1] += pv1*w4.y;
                    acc[m][1][2] += pv1*w4.z; acc[m][1][3] += pv1*w4.w;
                }
            }
        }
        __syncthreads();
        float gv[4], bv[4];
        #pragma unroll
        for (int oo=0;oo<4;++oo){ gv[oo]=g2[o4*4+oo]; bv[oo]=b2[o4*4+oo]; }
        #pragma unroll
        for (int m=0;m<5;++m){
            int q = qq + 8*m;
            if (q < 34) {
                #pragma unroll
                for (int oo=0;oo<4;++oo){
                    float v = (q<33) ? frelu(acc[m][1][oo]*gv[oo]+bv[oo]) : -1e30f;
                    if (q > 0) v = fmaxf(v, frelu(acc[m][0][oo]*gv[oo]+bv[oo]));
                    else if (q==0 && v < 0.f) v = frelu(acc[m][1][oo]*gv[oo]+bv[oo]);
                    sm[4864 + (o4*4+oo)*44 + q + 5] = v;
                }
            }
        }
    }
    __syncthreads();

    // ---- conv3 + pool -> aflat[o*18+q], o<32, q<18 ; K=(128c x 8k), c-chunks of 4
    {
        const int o16 = t & 15, qq = t >> 4;   // o = o16*2+oo ; qq in [0,16)
        float acc[2][2][2];
        acc[0][0][0]=acc[0][0][1]=acc[0][1][0]=acc[0][1][1]=0.f;
        acc[1][0][0]=acc[1][0][1]=acc[1][1][0]=acc[1][1][1]=0.f;
        int p0m[2];
        p0m[0] = 2*qq - 1;
        { int q = qq + 16; if (q > 17) q = 17; p0m[1] = 2*q - 1; }
        for (int cc = 0; cc < 32; ++cc) {
            __syncthreads();
            #pragma unroll
            for (int r = 0; r < 4; ++r) {        // stage w3 chunk: [ck][36] o-minor
                int j = r*256 + t;
                int ck = j >> 5, o = j & 31;
                sm[10640 + ck*36 + o] = w3[o*1024 + cc*32 + ck];
            }
            __syncthreads();
            for (int ck = 0; ck < 32; ++ck) {
                float2 w2r = *(const float2*)&sm[10640 + ck*36 + o16*2];
                int c = cc*4 + (ck>>3), k = ck & 7;
                const float* pc = &sm[4864 + c*44 + k + 1];
                #pragma unroll
                for (int m=0;m<2;++m){
                    float pv0 = pc[p0m[m]];
                    float pv1 = pc[p0m[m]+1];
                    acc[m][0][0] += pv0*w2r.x; acc[m][0][1] += pv0*w2r.y;
                    acc[m][1][0] += pv1*w2r.x; acc[m][1][1] += pv1*w2r.y;
                }
            }
        }
        __syncthreads();
        float gv[2]={g3[o16*2],g3[o16*2+1]}, bv[2]={b3[o16*2],b3[o16*2+1]};
        #pragma unroll
        for (int m=0;m<2;++m){
            int q = qq + 16*m;
            if (q < 18) {
                #pragma unroll
                for (int oo=0;oo<2;++oo){
                    float v = frelu(acc[m][1][oo]*gv[oo]+bv[oo]);   // pos1 always valid
                    if (q > 0) v = fmaxf(v, frelu(acc[m][0][oo]*gv[oo]+bv[oo]));
                    sm[14864 + (o16*2+oo)*18 + q] = v;
                }
            }
        }
    }
    __syncthreads();

    // ---- map2: a2[s,j] = (aflat . m2w[:,j] + m2b)*m2g + m2bb
    {
        const int j = t & 127, half = t >> 7;
        float acc = 0.f;
        const int f0 = half*288;
        for (int f = 0; f < 288; ++f)
            acc += sm[14864 + f0 + f] * m2w[(size_t)(f0+f)*128 + j];
        sm[10640 + t] = acc;
        __syncthreads();
        if (t < 128) {
            float tot = sm[10640 + t] + sm[10640 + 128 + t];
            a2[(size_t)s*128 + t] = (tot + m2b[t]) * m2g[t] + m2bb[t];
        }
    }
}

// ================= K2: build X[b,i,d] from a2 + positional encoding =================
__global__ __launch_bounds__(256) void k_buildx(const float* __restrict__ a2, float* __restrict__ X)
{
    int e = blockIdx.x*256 + threadIdx.x;    // < 524288
    int b = e >> 17;
    int r = e & 131071;
    int i = r >> 7, d = r & 127;
    int row = b*1024 + (d & 7)*128 + (i >> 3);
    int col = (i & 7)*16 + (d >> 3);
    float v = a2[row*128 + col];
    int per = b*1024 + (i & 7)*128 + d;
    int pc  = i >> 3;
    int m = pc >> 1;
    double dv = exp((double)(2*m) * (-9.210340371976184/128.0));  // ln(1e4)
    double ang = (double)per * dv;
    float pe = (pc & 1) ? (float)cos(ang) : (float)sin(ang);
    X[e] = v + pe;
}

// ================= K3: H = X @ gw + gb =================
__global__ __launch_bounds__(256) void k_hmat(const float* __restrict__ X, const float* __restrict__ gw,
                                              const float* __restrict__ gb, float* __restrict__ H)
{
    int e = blockIdx.x*256 + threadIdx.x;
    int srow = e >> 7, j = e & 127;
    const float* xr = X + (size_t)srow*128;
    float acc = gb[j];
    for (int k = 0; k < 128; ++k) acc += xr[k] * gw[k*128 + j];
    H[e] = acc;
}

// ================= K4: S = lrelu(H H^T - 1e8*I), 64x64 tiles =================
__global__ __launch_bounds__(256) void k_scores(const float* __restrict__ H, float* __restrict__ S)
{
    __shared__ __align__(16) float HiT[64*68];
    __shared__ __align__(16) float HjT[64*68];
    const int b = blockIdx.z;
    const int i0 = blockIdx.y * 64, j0 = blockIdx.x * 64;
    const int t = threadIdx.x;
    const int kk = t & 63, ilg = t >> 6;
    const int jg = t & 15, ig = t >> 4;
    float acc[4][4] = {};
    const float* Hb = H + (size_t)b*1024*128;
    for (int k0 = 0; k0 < 128; k0 += 64) {
        __syncthreads();
        #pragma unroll
        for (int m2 = 0; m2 < 16; ++m2) {
            int il = ilg*16 + m2;
            HiT[kk*68 + il] = Hb[(size_t)(i0+il)*128 + k0 + kk];
            HjT[kk*68 + il] = Hb[(size_t)(j0+il)*128 + k0 + kk];
        }
        __syncthreads();
        for (int k = 0; k < 64; ++k) {
            float4 a4 = *(const float4*)&HiT[k*68 + ig*4];
            float4 b4 = *(const float4*)&HjT[k*68 + jg*4];
            float av[4] = {a4.x, a4.y, a4.z, a4.w};
            float bv[4] = {b4.x, b4.y, b4.z, b4.w};
            #pragma unroll
            for (int ii = 0; ii < 4; ++ii)
                #pragma unroll
                for (int jj = 0; jj < 4; ++jj) acc[ii][jj] += av[ii]*bv[jj];
        }
    }
    float* Sb = S + (size_t)b*1024*1024;
    #pragma unroll
    for (int ii = 0; ii < 4; ++ii) {
        int i = i0 + ig*4 + ii;
        float vv[4];
        #pragma unroll
        for (int jj = 0; jj < 4; ++jj) {
            int j = j0 + jg*4 + jj;
            float x = acc[ii][jj];
            if (i == j) x -= 1e8f;
            vv[jj] = lrelu(x);
        }
        *(float4*)&Sb[(size_t)i*1024 + j0 + jg*4] = make_float4(vv[0],vv[1],vv[2],vv[3]);
    }
}

// ================= K5: row softmax in place (eye added later) =================
__global__ __launch_bounds__(256) void k_softmax(float* __restrict__ S)
{
    __shared__ float red[256];
    const int b = blockIdx.y, i = blockIdx.x, t = threadIdx.x;
    float* row = S + (size_t)b*1024*1024 + (size_t)i*1024;
    float4 v = *(const float4*)&row[t*4];
    float mx = fmaxf(fmaxf(v.x,v.y), fmaxf(v.z,v.w));
    red[t] = mx; __syncthreads();
    for (int s2 = 128; s2 > 0; s2 >>= 1) { if (t < s2) red[t] = fmaxf(red[t], red[t+s2]); __syncthreads(); }
    mx = red[0]; __syncthreads();
    float e0 = expf(v.x-mx), e1 = expf(v.y-mx), e2 = expf(v.z-mx), e3 = expf(v.w-mx);
    red[t] = e0+e1+e2+e3; __syncthreads();
    for (int s2 = 128; s2 > 0; s2 >>= 1) { if (t < s2) red[t] += red[t+s2]; __syncthreads(); }
    float inv = 1.f / red[0];
    *(float4*)&row[t*4] = make_float4(e0*inv, e1*inv, e2*inv, e3*inv);
}

// ================= K6: P = (S+I) @ (X*bng+bnb) =================
__global__ __launch_bounds__(256) void k_pv(const float* __restrict__ S, const float* __restrict__ X,
                                            const float* __restrict__ bng, const float* __restrict__ bnb,
                                            float* __restrict__ P)
{
    __shared__ __align__(16) float Sl[16*65];
    __shared__ __align__(16) float Xl[64*132];
    const int b = blockIdx.y, i0 = blockIdx.x*16, t = threadIdx.x;
    const int il = t >> 4, dg = t & 15;
    const int sj = t & 63, sil = t >> 6;
    const int xd = t & 127, xj = t >> 7;
    const float bg = bng[xd], bb = bnb[xd];
    float acc[8] = {};
    const float* Sb = S + (size_t)b*1024*1024;
    const float* Xb = X + (size_t)b*1024*128;
    for (int c = 0; c < 16; ++c) {
        int jb = c*64;
        __syncthreads();
        #pragma unroll
        for (int m2 = 0; m2 < 4; ++m2) {
            int r2 = sil*4 + m2;
            Sl[r2*65 + sj] = Sb[(size_t)(i0+r2)*1024 + jb + sj];
        }
        #pragma unroll
        for (int m2 = 0; m2 < 32; ++m2) {
            int jc = xj + 2*m2;
            Xl[jc*132 + xd] = Xb[(size_t)(jb+jc)*128 + xd] * bg + bb;
        }
        __syncthreads();
        for (int jc = 0; jc < 64; ++jc) {
            float sv = Sl[il*65 + jc];
            float4 x0 = *(const float4*)&Xl[jc*132 + dg*8];
            float4 x1 = *(const float4*)&Xl[jc*132 + dg*8 + 4];
            acc[0] += sv*x0.x; acc[1] += sv*x0.y; acc[2] += sv*x0.z; acc[3] += sv*x0.w;
            acc[4] += sv*x1.x; acc[5] += sv*x1.y; acc[6] += sv*x1.z; acc[7] += sv*x1.w;
        }
    }
    int i = i0 + il;
    const float* xr = Xb + (size_t)i*128 + dg*8;
    float* pr = P + (size_t)(b*1024 + i)*128 + dg*8;
    #pragma unroll
    for (int z = 0; z < 8; ++z) {
        float xv = xr[z] * bng[dg*8+z] + bnb[dg*8+z];
        pr[z] = acc[z] + xv;
    }
}

// ================= K7: O = lrelu(P @ tw + tb) =================
__global__ __launch_bounds__(256) void k_tproj(const float* __restrict__ P, const float* __restrict__ tw,
                                               const float* __restrict__ tb, float* __restrict__ O)
{
    int idx = blockIdx.x*256 + threadIdx.x;   // 4096*64
    int srow = idx >> 6, e = idx & 63;
    const float* pr = P + (size_t)srow*128;
    float acc = tb[e];
    for (int d = 0; d < 128; ++d) acc += pr[d] * tw[d*64 + e];
    O[idx] = lrelu(acc);
}

// ================= K8: fc1 partial sums (deterministic, no atomics) =================
__global__ __launch_bounds__(256) void k_fc1(const float* __restrict__ O1, const float* __restrict__ O2,
                                             const float* __restrict__ w, float* __restrict__ pbuf)
{
    __shared__ float red[4*512];
    const int t = threadIdx.x;
    const int wv = t >> 6, l = t & 63;
    const int gwid = blockIdx.x*4 + wv;   // 0..2047
    float acc[4][2] = {};
    int base = gwid*64;
    for (int tt = 0; tt < 64; ++tt) {
        int row = base + tt;
        float2 wvv = *(const float2*)&w[(size_t)row*128 + l*2];
        #pragma unroll
        for (int b = 0; b < 4; ++b) {
            float fb = (row < 65536) ? O1[b*65536 + row] : O2[b*65536 + row - 65536];
            acc[b][0] += fb * wvv.x;
            acc[b][1] += fb * wvv.y;
        }
    }
    #pragma unroll
    for (int b = 0; b < 4; ++b) {
        red[wv*512 + b*128 + l*2]   = acc[b][0];
        red[wv*512 + b*128 + l*2+1] = acc[b][1];
    }
    __syncthreads();
    for (int rep = 0; rep < 2; ++rep) {
        int col = rep*256 + t;
        pbuf[(size_t)blockIdx.x*512 + col] = red[col] + red[512+col] + red[1024+col] + red[1536+col];
    }
}

// ================= K9: reduce fc1 partials + fc2/fc3/fc4 head =================
__global__ __launch_bounds__(256) void k_head(const float* __restrict__ pbuf,
    const float* __restrict__ fc1b, const float* __restrict__ fc2w, const float* __restrict__ fc2b,
    const float* __restrict__ fc3w, const float* __restrict__ fc3b,
    const float* __restrict__ fc4w, const float* __restrict__ fc4b,
    float* __restrict__ out)
{
    __shared__ float r1[512], r2[512], r3[256];
    const int t = threadIdx.x;
    for (int rep = 0; rep < 2; ++rep) {
        int idx = rep*256 + t;
        float acc = 0.f;
        for (int blk = 0; blk < 512; ++blk) acc += pbuf[(size_t)blk*512 + idx];
        r1[idx] = frelu(acc + fc1b[idx & 127]);
    }
    __syncthreads();
    for (int rep = 0; rep < 2; ++rep) {
        int idx = rep*256 + t;
        int b = idx >> 7, j = idx & 127;
        float acc = fc2b[j];
        for (int k = 0; k < 128; ++k) acc += r1[b*128+k]*fc2w[k*128+j];
        r2[idx] = frelu(acc);
    }
    __syncthreads();
    {
        int b = t >> 6, e2 = t & 63;
        float acc = fc3b[e2];
        for (int k = 0; k < 128; ++k) acc += r2[b*128+k]*fc3w[k*64+e2];
        r3[t] = frelu(acc);
    }
    __syncthreads();
    if (t < 24) {
        int b = t/6, c = t%6;
        float acc = fc4b[c];
        for (int k = 0; k < 64; ++k) acc += r3[b*64+k]*fc4w[k*6+c];
        out[b*6+c] = acc;
    }
}

extern "C" void kernel_launch(void* const* d_in, const int* in_sizes, int n_in,
                              void* d_out, int out_size, void* d_ws, size_t ws_size,
                              hipStream_t stream)
{
    (void)in_sizes; (void)n_in; (void)out_size; (void)ws_size;
    const float* xenc = (const float*)d_in[0];
    const float* w1   = (const float*)d_in[4];
    const float* g1   = (const float*)d_in[5];
    const float* b1   = (const float*)d_in[6];
    const float* w2   = (const float*)d_in[7];
    const float* g2   = (const float*)d_in[8];
    const float* b2   = (const float*)d_in[9];
    const float* w3   = (const float*)d_in[10];
    const float* g3   = (const float*)d_in[11];
    const float* b3   = (const float*)d_in[12];
    const float* m2w  = (const float*)d_in[13];
    const float* m2b  = (const float*)d_in[14];
    const float* m2g  = (const float*)d_in[15];
    const float* m2bb = (const float*)d_in[16];
    const float* g1w  = (const float*)d_in[17];
    const float* g1b  = (const float*)d_in[18];
    const float* m1g  = (const float*)d_in[19];
    const float* m1b  = (const float*)d_in[20];
    const float* t1w  = (const float*)d_in[21];
    const float* t1b  = (const float*)d_in[22];
    const float* g2w  = (const float*)d_in[23];
    const float* g2bv = (const float*)d_in[24];
    const float* mm2g = (const float*)d_in[25];
    const float* mm2b = (const float*)d_in[26];
    const float* t2w  = (const float*)d_in[27];
    const float* t2b  = (const float*)d_in[28];
    const float* fc1w = (const float*)d_in[29];
    const float* fc1b = (const float*)d_in[30];
    const float* fc2w = (const float*)d_in[31];
    const float* fc2b = (const float*)d_in[32];
    const float* fc3w = (const float*)d_in[33];
    const float* fc3b = (const float*)d_in[34];
    const float* fc4w = (const float*)d_in[35];
    const float* fc4b = (const float*)d_in[36];

    char* ws = (char*)d_ws;
    float* a2   = (float*)(ws);                 // 2 MB
    float* X    = (float*)(ws + (2u<<20));      // 2 MB
    float* H    = (float*)(ws + (4u<<20));      // 2 MB
    float* S    = (float*)(ws + (6u<<20));      // 16 MB
    float* P    = (float*)(ws + (22u<<20));     // 2 MB
    float* O1   = (float*)(ws + (24u<<20));     // 1 MB
    float* O2   = (float*)(ws + (25u<<20));     // 1 MB
    float* pbuf = (float*)(ws + (26u<<20));     // 1 MB

    k_conv<<<4096, 256, 0, stream>>>(xenc, w1,g1,b1, w2,g2,b2, w3,g3,b3, m2w,m2b,m2g,m2bb, a2);
    k_buildx<<<2048, 256, 0, stream>>>(a2, X);
    // branch 1
    k_hmat   <<<2048, 256, 0, stream>>>(X, g1w, g1b, H);
    k_scores <<<dim3(16,16,4), 256, 0, stream>>>(H, S);
    k_softmax<<<dim3(1024,4), 256, 0, stream>>>(S);
    k_pv     <<<dim3(64,4), 256, 0, stream>>>(S, X, m1g, m1b, P);
    k_tproj  <<<1024, 256, 0, stream>>>(P, t1w, t1b, O1);
    // branch 2
    k_hmat   <<<2048, 256, 0, stream>>>(X, g2w, g2bv, H);
    k_scores <<<dim3(16,16,4), 256, 0, stream>>>(H, S);
    k_softmax<<<dim3(1024,4), 256, 0, stream>>>(S);
    k_pv     <<<dim3(64,4), 256, 0, stream>>>(S, X, mm2g, mm2b, P);
    k_tproj  <<<1024, 256, 0, stream>>>(P, t2w, t2b, O2);
    // head
    k_fc1 <<<512, 256, 0, stream>>>(O1, O2, fc1w, pbuf);
    k_head<<<1, 256, 0, stream>>>(pbuf, fc1b, fc2w, fc2b, fc3w, fc3b, fc4w, fc4b, (float*)d_out);
}

// Round 2
// 402.693 us; speedup vs baseline: 3.6617x; 3.6617x over previous
//
#include <hip/hip_runtime.h>
#include <math.h>

#define NEG 0.01f
__device__ __forceinline__ float lrelu(float v){ return v > 0.f ? v : NEG*v; }
__device__ __forceinline__ float frelu(float v){ return v > 0.f ? v : 0.f; }

typedef __attribute__((ext_vector_type(8))) short bf16x8;
typedef __attribute__((ext_vector_type(4))) float f32x4;

__device__ __forceinline__ unsigned short f2bf(float x){
    unsigned int u = __float_as_uint(x);
    unsigned int r = (u + 0x7FFFu + ((u>>16)&1u)) >> 16;
    return (unsigned short)r;
}
__device__ __forceinline__ float bf2f(unsigned short h){
    return __uint_as_float(((unsigned int)h) << 16);
}

// ============ K0: weight repack (frag-ready layouts, bf16) ============
// w2s[(((k*2+ks)*128+o)*4+q)*8+jj] = w2[o*512 + (ks*32+q*8+jj)*8 + k]
// w3s[(((k*4+ks)*32 +o)*4+q)*8+jj] = w3[o*1024 + (ks*32+q*8+jj)*8 + k]
// m2wbT[j*576+f] = m2w[f*128+j]
__global__ __launch_bounds__(256) void k_prep(const float* __restrict__ w2, const float* __restrict__ w3,
    const float* __restrict__ m2w,
    unsigned short* __restrict__ w2s, unsigned short* __restrict__ w3s, unsigned short* __restrict__ m2wbT)
{
    int gid = blockIdx.x*256 + threadIdx.x;
    if (gid < 73728) {
        int j = gid / 576, f = gid % 576;
        m2wbT[gid] = f2bf(m2w[f*128 + j]);
    }
    if (gid < 65536) {
        int jj = gid & 7, q = (gid>>3)&3, o = (gid>>5)&127, ks = (gid>>12)&1, k = gid>>13;
        int c = ks*32 + q*8 + jj;
        w2s[gid] = f2bf(w2[o*512 + c*8 + k]);
    }
    if (gid < 32768) {
        int jj = gid & 7, q = (gid>>3)&3, o = (gid>>5)&31, ks = (gid>>10)&3, k = gid>>12;
        int c = ks*32 + q*8 + jj;
        w3s[gid] = f2bf(w3[o*1024 + c*8 + k]);
    }
}

// ============ K1: fused conv stack, MFMA for conv2/conv3 ============
// one block per signal (4096), 256 threads = 4 waves.
// LDS: sigp f32[144] @0 (576B); p1T bf16[76][64] @576 (9728B, granule XOR row&7);
//      p2T bf16[42][128] @10304 (10752B, granule XOR row&15);
//      cbuf @21056 (17408B: conv2-out bf16[128][68], later conv3-out f32[32][36])
__global__ __launch_bounds__(256) void k_conv(
    const float* __restrict__ xenc,
    const float* __restrict__ w1, const float* __restrict__ g1, const float* __restrict__ b1,
    const unsigned short* __restrict__ w2s, const float* __restrict__ g2, const float* __restrict__ b2,
    const unsigned short* __restrict__ w3s, const float* __restrict__ g3, const float* __restrict__ b3,
    unsigned short* __restrict__ aflatG)
{
    __shared__ __align__(16) unsigned char smraw[38464];
    float* sigp = (float*)smraw;                           // [136]
    unsigned short* p1T = (unsigned short*)(smraw + 576);  // 76*64
    unsigned short* p2T = (unsigned short*)(smraw + 10304);// 42*128
    unsigned short* c2o = (unsigned short*)(smraw + 21056);// 128*68
    float* c3o = (float*)(smraw + 21056);                  // 32*36 (overlay, after c2o dead)

    const int t = threadIdx.x;
    const int s = blockIdx.x;

    // zero p1T + p2T (contiguous 20480B = 5120 u32) and sigp
    {
        unsigned int* zz = (unsigned int*)(smraw + 576);
        for (int i = t; i < 5120; i += 256) zz[i] = 0u;
        if (t < 136) sigp[t] = 0.f;
    }
    __syncthreads();
    if (t < 128) sigp[4 + t] = xenc[(size_t)s*128 + t];
    __syncthreads();

    // ---- conv1 (f32) + bn + relu + pool -> p1T (bf16, swizzled)
    {
        const int c = t & 63, qg = t >> 6;
        float wr[8];
        #pragma unroll
        for (int k = 0; k < 8; ++k) wr[k] = w1[c*8 + k];
        const float g = g1[c], b = b1[c];
        for (int m = 0; m < 17; ++m) {
            int q = qg + 4*m;
            if (q < 65) {
                float s1 = 0.f;
                #pragma unroll
                for (int k = 0; k < 8; ++k) s1 += sigp[2*q + k] * wr[k];
                float v = frelu(s1*g + b);
                if (q > 0) {
                    float s0 = 0.f;
                    #pragma unroll
                    for (int k = 0; k < 8; ++k) s0 += sigp[2*q - 1 + k] * wr[k];
                    v = fmaxf(v, frelu(s0*g + b));
                }
                int row = q + 4;
                p1T[row*64 + (((c>>3) ^ (row&7))<<3) + (c&7)] = f2bf(v);
            }
        }
    }
    __syncthreads();

    // ---- conv2: 8 shift-GEMMs, M=128(o), N=80(p, 66 valid), K=64(c) -> MFMA
    {
        const int wv = t >> 6, l = t & 63, lg = l >> 4, lr = l & 15;
        f32x4 acc[2][5] = {};
        for (int k = 0; k < 8; ++k) {
            for (int ks = 0; ks < 2; ++ks) {
                bf16x8 af[2];
                #pragma unroll
                for (int oi = 0; oi < 2; ++oi) {
                    int o = (wv*2 + oi)*16 + lr;
                    af[oi] = *(const bf16x8*)(w2s + ((((k*2 + ks)*128 + o)*4 + lg)<<3));
                }
                #pragma unroll
                for (int nt = 0; nt < 5; ++nt) {
                    int row = nt*16 + lr + k; row = row > 75 ? 75 : row;
                    int q = ks*4 + lg;
                    bf16x8 bfv = *(const bf16x8*)(p1T + row*64 + ((q ^ (row&7))<<3));
                    acc[0][nt] = __builtin_amdgcn_mfma_f32_16x16x32_bf16(af[0], bfv, acc[0][nt], 0,0,0);
                    acc[1][nt] = __builtin_amdgcn_mfma_f32_16x16x32_bf16(af[1], bfv, acc[1][nt], 0,0,0);
                }
            }
        }
        // epilogue: bn+relu -> c2o bf16 [o][68]
        #pragma unroll
        for (int oi = 0; oi < 2; ++oi) {
            #pragma unroll
            for (int nt = 0; nt < 5; ++nt) {
                #pragma unroll
                for (int r = 0; r < 4; ++r) {
                    int o = (wv*2 + oi)*16 + lg*4 + r;
                    int p = nt*16 + lr;
                    if (p < 66) {
                        float v = frelu(acc[oi][nt][r] * g2[o] + b2[o]);
                        c2o[o*68 + p] = f2bf(v);
                    }
                }
            }
        }
    }
    __syncthreads();

    // ---- pool2 -> p2T (bf16, swizzled). post-relu bf16 >= +0 so ushort max works.
    for (int idx = t; idx < 4352; idx += 256) {
        int o = idx & 127, q = idx >> 7;     // q < 34
        unsigned short v = (q <= 32) ? c2o[o*68 + 2*q] : (unsigned short)0;
        if (q > 0) { unsigned short v2 = c2o[o*68 + 2*q - 1]; v = (v2 > v) ? v2 : v; }
        int row = q + 4;
        p2T[row*128 + (((o>>3) ^ (row&15))<<3) + (o&7)] = v;
    }
    __syncthreads();

    // ---- conv3: 8 shift-GEMMs, M=32(o), N=48(p, 35 valid), K=128(c) -> MFMA
    {
        const int wv = t >> 6, l = t & 63, lg = l >> 4, lr = l & 15;
        const int ot = wv & 1, ntb = (wv >> 1) * 2;
        const int ncnt = (wv < 2) ? 2 : 1;
        f32x4 acc[2] = {};
        for (int k = 0; k < 8; ++k) {
            for (int ks = 0; ks < 4; ++ks) {
                int o = ot*16 + lr;
                bf16x8 af = *(const bf16x8*)(w3s + ((((k*4 + ks)*32 + o)*4 + lg)<<3));
                int q = ks*4 + lg;
                #pragma unroll
                for (int ni = 0; ni < 2; ++ni) {
                    if (ni < ncnt) {
                        int row = (ntb + ni)*16 + lr + k; row = row > 41 ? 41 : row;
                        bf16x8 bfv = *(const bf16x8*)(p2T + row*128 + ((q ^ (row&15))<<3));
                        acc[ni] = __builtin_amdgcn_mfma_f32_16x16x32_bf16(af, bfv, acc[ni], 0,0,0);
                    }
                }
            }
        }
        // epilogue: bn+relu -> c3o f32 [32][36]  (c2o fully consumed before this phase)
        #pragma unroll
        for (int ni = 0; ni < 2; ++ni) if (ni < ncnt) {
            #pragma unroll
            for (int r = 0; r < 4; ++r) {
                int o = ot*16 + lg*4 + r;
                int p = (ntb + ni)*16 + lr;
                if (p < 35) {
                    float v = frelu(acc[ni][r] * g3[o] + b3[o]);
                    c3o[o*36 + p] = v;
                }
            }
        }
    }
    __syncthreads();

    // ---- pool3 -> aflatG bf16 (global), order f = o*18+q
    for (int idx = t; idx < 576; idx += 256) {
        int o = idx / 18, q = idx % 18;
        float v = c3o[o*36 + 2*q];
        if (q > 0) v = fmaxf(v, c3o[o*36 + 2*q - 1]);
        aflatG[(size_t)s*576 + idx] = f2bf(v);
    }
}

// ============ K1b: map2 GEMM [4096x576]x[576x128] bf16 MFMA ============
__global__ __launch_bounds__(256) void k_map2(const unsigned short* __restrict__ aflatG,
    const unsigned short* __restrict__ m2wbT,
    const float* __restrict__ m2b, const float* __restrict__ m2g, const float* __restrict__ m2bb,
    float* __restrict__ a2)
{
    const int t = threadIdx.x, wv = t>>6, l = t&63, lg = l>>4, lr = l&15;
    const int s0 = blockIdx.x*64;
    f32x4 acc[8] = {};
    for (int ks = 0; ks < 18; ++ks) {
        bf16x8 a = *(const bf16x8*)(aflatG + (size_t)(s0 + wv*16 + lr)*576 + ks*32 + lg*8);
        #pragma unroll
        for (int nt = 0; nt < 8; ++nt) {
            bf16x8 b = *(const bf16x8*)(m2wbT + (size_t)(nt*16 + lr)*576 + ks*32 + lg*8);
            acc[nt] = __builtin_amdgcn_mfma_f32_16x16x32_bf16(a, b, acc[nt], 0,0,0);
        }
    }
    #pragma unroll
    for (int nt = 0; nt < 8; ++nt) {
        #pragma unroll
        for (int r = 0; r < 4; ++r) {
            int s2 = s0 + wv*16 + lg*4 + r;
            int j = nt*16 + lr;
            a2[(size_t)s2*128 + j] = (acc[nt][r] + m2b[j]) * m2g[j] + m2bb[j];
        }
    }
}

// ================= K2: build X[b,i,d] from a2 + positional encoding =================
__global__ __launch_bounds__(256) void k_buildx(const float* __restrict__ a2, float* __restrict__ X)
{
    int e = blockIdx.x*256 + threadIdx.x;    // < 524288
    int b = e >> 17;
    int r = e & 131071;
    int i = r >> 7, d = r & 127;
    int row = b*1024 + (d & 7)*128 + (i >> 3);
    int col = (i & 7)*16 + (d >> 3);
    float v = a2[row*128 + col];
    int per = b*1024 + (i & 7)*128 + d;
    int pc  = i >> 3;
    int m = pc >> 1;
    double dv = exp((double)(2*m) * (-9.210340371976184/128.0));  // ln(1e4)
    double ang = (double)per * dv;
    float pe = (pc & 1) ? (float)cos(ang) : (float)sin(ang);
    X[e] = v + pe;
}

// ================= K3: H = X @ gw + gb =================
__global__ __launch_bounds__(256) void k_hmat(const float* __restrict__ X, const float* __restrict__ gw,
                                              const float* __restrict__ gb, float* __restrict__ H)
{
    int e = blockIdx.x*256 + threadIdx.x;
    int srow = e >> 7, j = e & 127;
    const float* xr = X + (size_t)srow*128;
    float acc = gb[j];
    for (int k = 0; k < 128; ++k) acc += xr[k] * gw[k*128 + j];
    H[e] = acc;
}

// ================= K4: S = lrelu(H H^T - 1e8*I), 64x64 tiles =================
__global__ __launch_bounds__(256) void k_scores(const float* __restrict__ H, float* __restrict__ S)
{
    __shared__ __align__(16) float HiT[64*68];
    __shared__ __align__(16) float HjT[64*68];
    const int b = blockIdx.z;
    const int i0 = blockIdx.y * 64, j0 = blockIdx.x * 64;
    const int t = threadIdx.x;
    const int kk = t & 63, ilg = t >> 6;
    const int jg = t & 15, ig = t >> 4;
    float acc[4][4] = {};
    const float* Hb = H + (size_t)b*1024*128;
    for (int k0 = 0; k0 < 128; k0 += 64) {
        __syncthreads();
        #pragma unroll
        for (int m2 = 0; m2 < 16; ++m2) {
            int il = ilg*16 + m2;
            HiT[kk*68 + il] = Hb[(size_t)(i0+il)*128 + k0 + kk];
            HjT[kk*68 + il] = Hb[(size_t)(j0+il)*128 + k0 + kk];
        }
        __syncthreads();
        for (int k = 0; k < 64; ++k) {
            float4 a4 = *(const float4*)&HiT[k*68 + ig*4];
            float4 b4 = *(const float4*)&HjT[k*68 + jg*4];
            float av[4] = {a4.x, a4.y, a4.z, a4.w};
            float bv[4] = {b4.x, b4.y, b4.z, b4.w};
            #pragma unroll
            for (int ii = 0; ii < 4; ++ii)
                #pragma unroll
                for (int jj = 0; jj < 4; ++jj) acc[ii][jj] += av[ii]*bv[jj];
        }
    }
    float* Sb = S + (size_t)b*1024*1024;
    #pragma unroll
    for (int ii = 0; ii < 4; ++ii) {
        int i = i0 + ig*4 + ii;
        float vv[4];
        #pragma unroll
        for (int jj = 0; jj < 4; ++jj) {
            int j = j0 + jg*4 + jj;
            float x = acc[ii][jj];
            if (i == j) x -= 1e8f;
            vv[jj] = lrelu(x);
        }
        *(float4*)&Sb[(size_t)i*1024 + j0 + jg*4] = make_float4(vv[0],vv[1],vv[2],vv[3]);
    }
}

// ================= K5: row softmax in place (eye added later) =================
__global__ __launch_bounds__(256) void k_softmax(float* __restrict__ S)
{
    __shared__ float red[256];
    const int b = blockIdx.y, i = blockIdx.x, t = threadIdx.x;
    float* row = S + (size_t)b*1024*1024 + (size_t)i*1024;
    float4 v = *(const float4*)&row[t*4];
    float mx = fmaxf(fmaxf(v.x,v.y), fmaxf(v.z,v.w));
    red[t] = mx; __syncthreads();
    for (int s2 = 128; s2 > 0; s2 >>= 1) { if (t < s2) red[t] = fmaxf(red[t], red[t+s2]); __syncthreads(); }
    mx = red[0]; __syncthreads();
    float e0 = expf(v.x-mx), e1 = expf(v.y-mx), e2 = expf(v.z-mx), e3 = expf(v.w-mx);
    red[t] = e0+e1+e2+e3; __syncthreads();
    for (int s2 = 128; s2 > 0; s2 >>= 1) { if (t < s2) red[t] += red[t+s2]; __syncthreads(); }
    float inv = 1.f / red[0];
    *(float4*)&row[t*4] = make_float4(e0*inv, e1*inv, e2*inv, e3*inv);
}

// ================= K6: P = (S+I) @ (X*bng+bnb) =================
__global__ __launch_bounds__(256) void k_pv(const float* __restrict__ S, const float* __restrict__ X,
                                            const float* __restrict__ bng, const float* __restrict__ bnb,
                                            float* __restrict__ P)
{
    __shared__ __align__(16) float Sl[16*65];
    __shared__ __align__(16) float Xl[64*132];
    const int b = blockIdx.y, i0 = blockIdx.x*16, t = threadIdx.x;
    const int il = t >> 4, dg = t & 15;
    const int sj = t & 63, sil = t >> 6;
    const int xd = t & 127, xj = t >> 7;
    const float bg = bng[xd], bb = bnb[xd];
    float acc[8] = {};
    const float* Sb = S + (size_t)b*1024*1024;
    const float* Xb = X + (size_t)b*1024*128;
    for (int c = 0; c < 16; ++c) {
        int jb = c*64;
        __syncthreads();
        #pragma unroll
        for (int m2 = 0; m2 < 4; ++m2) {
            int r2 = sil*4 + m2;
            Sl[r2*65 + sj] = Sb[(size_t)(i0+r2)*1024 + jb + sj];
        }
        #pragma unroll
        for (int m2 = 0; m2 < 32; ++m2) {
            int jc = xj + 2*m2;
            Xl[jc*132 + xd] = Xb[(size_t)(jb+jc)*128 + xd] * bg + bb;
        }
        __syncthreads();
        for (int jc = 0; jc < 64; ++jc) {
            float sv = Sl[il*65 + jc];
            float4 x0 = *(const float4*)&Xl[jc*132 + dg*8];
            float4 x1 = *(const float4*)&Xl[jc*132 + dg*8 + 4];
            acc[0] += sv*x0.x; acc[1] += sv*x0.y; acc[2] += sv*x0.z; acc[3] += sv*x0.w;
            acc[4] += sv*x1.x; acc[5] += sv*x1.y; acc[6] += sv*x1.z; acc[7] += sv*x1.w;
        }
    }
    int i = i0 + il;
    const float* xr = Xb + (size_t)i*128 + dg*8;
    float* pr = P + (size_t)(b*1024 + i)*128 + dg*8;
    #pragma unroll
    for (int z = 0; z < 8; ++z) {
        float xv = xr[z] * bng[dg*8+z] + bnb[dg*8+z];
        pr[z] = acc[z] + xv;
    }
}

// ================= K7: O = lrelu(P @ tw + tb) =================
__global__ __launch_bounds__(256) void k_tproj(const float* __restrict__ P, const float* __restrict__ tw,
                                               const float* __restrict__ tb, float* __restrict__ O)
{
    int idx = blockIdx.x*256 + threadIdx.x;   // 4096*64
    int srow = idx >> 6, e = idx & 63;
    const float* pr = P + (size_t)srow*128;
    float acc = tb[e];
    for (int d = 0; d < 128; ++d) acc += pr[d] * tw[d*64 + e];
    O[idx] = lrelu(acc);
}

// ================= K8: fc1 partial sums (deterministic, no atomics) =================
__global__ __launch_bounds__(256) void k_fc1(const float* __restrict__ O1, const float* __restrict__ O2,
                                             const float* __restrict__ w, float* __restrict__ pbuf)
{
    __shared__ float red[4*512];
    const int t = threadIdx.x;
    const int wv = t >> 6, l = t & 63;
    const int gwid = blockIdx.x*4 + wv;   // 0..2047
    float acc[4][2] = {};
    int base = gwid*64;
    for (int tt = 0; tt < 64; ++tt) {
        int row = base + tt;
        float2 wvv = *(const float2*)&w[(size_t)row*128 + l*2];
        #pragma unroll
        for (int b = 0; b < 4; ++b) {
            float fb = (row < 65536) ? O1[b*65536 + row] : O2[b*65536 + row - 65536];
            acc[b][0] += fb * wvv.x;
            acc[b][1] += fb * wvv.y;
        }
    }
    #pragma unroll
    for (int b = 0; b < 4; ++b) {
        red[wv*512 + b*128 + l*2]   = acc[b][0];
        red[wv*512 + b*128 + l*2+1] = acc[b][1];
    }
    __syncthreads();
    for (int rep = 0; rep < 2; ++rep) {
        int col = rep*256 + t;
        pbuf[(size_t)blockIdx.x*512 + col] = red[col] + red[512+col] + red[1024+col] + red[1536+col];
    }
}

// ================= K9: reduce fc1 partials + fc2/fc3/fc4 head =================
__global__ __launch_bounds__(256) void k_head(const float* __restrict__ pbuf,
    const float* __restrict__ fc1b, const float* __restrict__ fc2w, const float* __restrict__ fc2b,
    const float* __restrict__ fc3w, const float* __restrict__ fc3b,
    const float* __restrict__ fc4w, const float* __restrict__ fc4b,
    float* __restrict__ out)
{
    __shared__ float r1[512], r2[512], r3[256];
    const int t = threadIdx.x;
    for (int rep = 0; rep < 2; ++rep) {
        int idx = rep*256 + t;
        float acc = 0.f;
        for (int blk = 0; blk < 512; ++blk) acc += pbuf[(size_t)blk*512 + idx];
        r1[idx] = frelu(acc + fc1b[idx & 127]);
    }
    __syncthreads();
    for (int rep = 0; rep < 2; ++rep) {
        int idx = rep*256 + t;
        int b = idx >> 7, j = idx & 127;
        float acc = fc2b[j];
        for (int k = 0; k < 128; ++k) acc += r1[b*128+k]*fc2w[k*128+j];
        r2[idx] = frelu(acc);
    }
    __syncthreads();
    {
        int b = t >> 6, e2 = t & 63;
        float acc = fc3b[e2];
        for (int k = 0; k < 128; ++k) acc += r2[b*128+k]*fc3w[k*64+e2];
        r3[t] = frelu(acc);
    }
    __syncthreads();
    if (t < 24) {
        int b = t/6, c = t%6;
        float acc = fc4b[c];
        for (int k = 0; k < 64; ++k) acc += r3[b*64+k]*fc4w[k*6+c];
        out[b*6+c] = acc;
    }
}

extern "C" void kernel_launch(void* const* d_in, const int* in_sizes, int n_in,
                              void* d_out, int out_size, void* d_ws, size_t ws_size,
                              hipStream_t stream)
{
    (void)in_sizes; (void)n_in; (void)out_size; (void)ws_size;
    const float* xenc = (const float*)d_in[0];
    const float* w1   = (const float*)d_in[4];
    const float* g1   = (const float*)d_in[5];
    const float* b1   = (const float*)d_in[6];
    const float* w2   = (const float*)d_in[7];
    const float* g2   = (const float*)d_in[8];
    const float* b2   = (const float*)d_in[9];
    const float* w3   = (const float*)d_in[10];
    const float* g3   = (const float*)d_in[11];
    const float* b3   = (const float*)d_in[12];
    const float* m2w  = (const float*)d_in[13];
    const float* m2b  = (const float*)d_in[14];
    const float* m2g  = (const float*)d_in[15];
    const float* m2bb = (const float*)d_in[16];
    const float* g1w  = (const float*)d_in[17];
    const float* g1b  = (const float*)d_in[18];
    const float* m1g  = (const float*)d_in[19];
    const float* m1b  = (const float*)d_in[20];
    const float* t1w  = (const float*)d_in[21];
    const float* t1b  = (const float*)d_in[22];
    const float* g2w  = (const float*)d_in[23];
    const float* g2bv = (const float*)d_in[24];
    const float* mm2g = (const float*)d_in[25];
    const float* mm2b = (const float*)d_in[26];
    const float* t2w  = (const float*)d_in[27];
    const float* t2b  = (const float*)d_in[28];
    const float* fc1w = (const float*)d_in[29];
    const float* fc1b = (const float*)d_in[30];
    const float* fc2w = (const float*)d_in[31];
    const float* fc2b = (const float*)d_in[32];
    const float* fc3w = (const float*)d_in[33];
    const float* fc3b = (const float*)d_in[34];
    const float* fc4w = (const float*)d_in[35];
    const float* fc4b = (const float*)d_in[36];

    char* ws = (char*)d_ws;
    float* a2   = (float*)(ws);                 // 2 MB
    float* X    = (float*)(ws + (2u<<20));      // 2 MB
    float* H    = (float*)(ws + (4u<<20));      // 2 MB
    float* S    = (float*)(ws + (6u<<20));      // 16 MB
    float* P    = (float*)(ws + (22u<<20));     // 2 MB
    float* O1   = (float*)(ws + (24u<<20));     // 1 MB
    float* O2   = (float*)(ws + (25u<<20));     // 1 MB
    float* pbuf = (float*)(ws + (26u<<20));     // 1 MB
    // transient buffers overlaid on S's region (all dead before k_scores writes S)
    unsigned short* aflatG = (unsigned short*)(ws + (6u<<20));             // 4.72 MB
    unsigned short* w2s    = (unsigned short*)(ws + (6u<<20) + 5242880);   // 128 KB
    unsigned short* w3s    = (unsigned short*)(ws + (6u<<20) + 5242880 + 131072);  // 64 KB
    unsigned short* m2wbT  = (unsigned short*)(ws + (6u<<20) + 5242880 + 196608);  // 144 KB

    k_prep<<<288, 256, 0, stream>>>(w2, w3, m2w, w2s, w3s, m2wbT);
    k_conv<<<4096, 256, 0, stream>>>(xenc, w1,g1,b1, w2s,g2,b2, w3s,g3,b3, aflatG);
    k_map2<<<64, 256, 0, stream>>>(aflatG, m2wbT, m2b, m2g, m2bb, a2);
    k_buildx<<<2048, 256, 0, stream>>>(a2, X);
    // branch 1
    k_hmat   <<<2048, 256, 0, stream>>>(X, g1w, g1b, H);
    k_scores <<<dim3(16,16,4), 256, 0, stream>>>(H, S);
    k_softmax<<<dim3(1024,4), 256, 0, stream>>>(S);
    k_pv     <<<dim3(64,4), 256, 0, stream>>>(S, X, m1g, m1b, P);
    k_tproj  <<<1024, 256, 0, stream>>>(P, t1w, t1b, O1);
    // branch 2
    k_hmat   <<<2048, 256, 0, stream>>>(X, g2w, g2bv, H);
    k_scores <<<dim3(16,16,4), 256, 0, stream>>>(H, S);
    k_softmax<<<dim3(1024,4), 256, 0, stream>>>(S);
    k_pv     <<<dim3(64,4), 256, 0, stream>>>(S, X, mm2g, mm2b, P);
    k_tproj  <<<1024, 256, 0, stream>>>(P, t2w, t2b, O2);
    // head
    k_fc1 <<<512, 256, 0, stream>>>(O1, O2, fc1w, pbuf);
    k_head<<<1, 256, 0, stream>>>(pbuf, fc1b, fc2w, fc2b, fc3w, fc3b, fc4w, fc4b, (float*)d_out);
}

// Round 5
// 368.519 us; speedup vs baseline: 4.0012x; 1.0927x over previous
//
#include <hip/hip_runtime.h>
#include <math.h>

#define NEG 0.01f
__device__ __forceinline__ float lrelu(float v){ return v > 0.f ? v : NEG*v; }
__device__ __forceinline__ float frelu(float v){ return v > 0.f ? v : 0.f; }

typedef __attribute__((ext_vector_type(8))) short bf16x8;
typedef __attribute__((ext_vector_type(4))) float f32x4;

__device__ __forceinline__ unsigned short f2bf(float x){
    unsigned int u = __float_as_uint(x);
    unsigned int r = (u + 0x7FFFu + ((u>>16)&1u)) >> 16;
    return (unsigned short)r;
}
__device__ __forceinline__ float bf2f(unsigned short h){
    return __uint_as_float(((unsigned int)h) << 16);
}

// ============ K0: weight repack (frag-ready layouts, bf16) ============
__global__ __launch_bounds__(256) void k_prep(const float* __restrict__ w2, const float* __restrict__ w3,
    const float* __restrict__ m2w,
    unsigned short* __restrict__ w2s, unsigned short* __restrict__ w3s, unsigned short* __restrict__ m2wbT)
{
    int gid = blockIdx.x*256 + threadIdx.x;
    if (gid < 73728) {
        int j = gid / 576, f = gid % 576;
        m2wbT[gid] = f2bf(m2w[f*128 + j]);
    }
    if (gid < 65536) {
        int jj = gid & 7, q = (gid>>3)&3, o = (gid>>5)&127, ks = (gid>>12)&1, k = gid>>13;
        int c = ks*32 + q*8 + jj;
        w2s[gid] = f2bf(w2[o*512 + c*8 + k]);
    }
    if (gid < 32768) {
        int jj = gid & 7, q = (gid>>3)&3, o = (gid>>5)&31, ks = (gid>>10)&3, k = gid>>12;
        int c = ks*32 + q*8 + jj;
        w3s[gid] = f2bf(w3[o*1024 + c*8 + k]);
    }
}

// ============ K1: fused conv stack, MFMA for conv2/conv3 (validated r2) ============
__global__ __launch_bounds__(256) void k_conv(
    const float* __restrict__ xenc,
    const float* __restrict__ w1, const float* __restrict__ g1, const float* __restrict__ b1,
    const unsigned short* __restrict__ w2s, const float* __restrict__ g2, const float* __restrict__ b2,
    const unsigned short* __restrict__ w3s, const float* __restrict__ g3, const float* __restrict__ b3,
    unsigned short* __restrict__ aflatG)
{
    __shared__ __align__(16) unsigned char smraw[38464];
    float* sigp = (float*)smraw;
    unsigned short* p1T = (unsigned short*)(smraw + 576);
    unsigned short* p2T = (unsigned short*)(smraw + 10304);
    unsigned short* c2o = (unsigned short*)(smraw + 21056);
    float* c3o = (float*)(smraw + 21056);

    const int t = threadIdx.x;
    const int s = blockIdx.x;

    {
        unsigned int* zz = (unsigned int*)(smraw + 576);
        for (int i = t; i < 5120; i += 256) zz[i] = 0u;
        if (t < 136) sigp[t] = 0.f;
    }
    __syncthreads();
    if (t < 128) sigp[4 + t] = xenc[(size_t)s*128 + t];
    __syncthreads();

    {   // conv1 f32 + bn + relu + pool -> p1T (bf16, swizzled)
        const int c = t & 63, qg = t >> 6;
        float wr[8];
        #pragma unroll
        for (int k = 0; k < 8; ++k) wr[k] = w1[c*8 + k];
        const float g = g1[c], b = b1[c];
        for (int m = 0; m < 17; ++m) {
            int q = qg + 4*m;
            if (q < 65) {
                float s1 = 0.f;
                #pragma unroll
                for (int k = 0; k < 8; ++k) s1 += sigp[2*q + k] * wr[k];
                float v = frelu(s1*g + b);
                if (q > 0) {
                    float s0 = 0.f;
                    #pragma unroll
                    for (int k = 0; k < 8; ++k) s0 += sigp[2*q - 1 + k] * wr[k];
                    v = fmaxf(v, frelu(s0*g + b));
                }
                int row = q + 4;
                p1T[row*64 + (((c>>3) ^ (row&7))<<3) + (c&7)] = f2bf(v);
            }
        }
    }
    __syncthreads();

    {   // conv2 MFMA
        const int wv = t >> 6, l = t & 63, lg = l >> 4, lr = l & 15;
        f32x4 acc[2][5] = {};
        for (int k = 0; k < 8; ++k) {
            for (int ks = 0; ks < 2; ++ks) {
                bf16x8 af[2];
                #pragma unroll
                for (int oi = 0; oi < 2; ++oi) {
                    int o = (wv*2 + oi)*16 + lr;
                    af[oi] = *(const bf16x8*)(w2s + ((((k*2 + ks)*128 + o)*4 + lg)<<3));
                }
                #pragma unroll
                for (int nt = 0; nt < 5; ++nt) {
                    int row = nt*16 + lr + k; row = row > 75 ? 75 : row;
                    int q = ks*4 + lg;
                    bf16x8 bfv = *(const bf16x8*)(p1T + row*64 + ((q ^ (row&7))<<3));
                    acc[0][nt] = __builtin_amdgcn_mfma_f32_16x16x32_bf16(af[0], bfv, acc[0][nt], 0,0,0);
                    acc[1][nt] = __builtin_amdgcn_mfma_f32_16x16x32_bf16(af[1], bfv, acc[1][nt], 0,0,0);
                }
            }
        }
        #pragma unroll
        for (int oi = 0; oi < 2; ++oi)
            #pragma unroll
            for (int nt = 0; nt < 5; ++nt)
                #pragma unroll
                for (int r = 0; r < 4; ++r) {
                    int o = (wv*2 + oi)*16 + lg*4 + r;
                    int p = nt*16 + lr;
                    if (p < 66) c2o[o*68 + p] = f2bf(frelu(acc[oi][nt][r] * g2[o] + b2[o]));
                }
    }
    __syncthreads();

    for (int idx = t; idx < 4352; idx += 256) {   // pool2
        int o = idx & 127, q = idx >> 7;
        unsigned short v = (q <= 32) ? c2o[o*68 + 2*q] : (unsigned short)0;
        if (q > 0) { unsigned short v2 = c2o[o*68 + 2*q - 1]; v = (v2 > v) ? v2 : v; }
        int row = q + 4;
        p2T[row*128 + (((o>>3) ^ (row&15))<<3) + (o&7)] = v;
    }
    __syncthreads();

    {   // conv3 MFMA
        const int wv = t >> 6, l = t & 63, lg = l >> 4, lr = l & 15;
        const int ot = wv & 1, ntb = (wv >> 1) * 2;
        const int ncnt = (wv < 2) ? 2 : 1;
        f32x4 acc[2] = {};
        for (int k = 0; k < 8; ++k) {
            for (int ks = 0; ks < 4; ++ks) {
                int o = ot*16 + lr;
                bf16x8 af = *(const bf16x8*)(w3s + ((((k*4 + ks)*32 + o)*4 + lg)<<3));
                int q = ks*4 + lg;
                #pragma unroll
                for (int ni = 0; ni < 2; ++ni) {
                    if (ni < ncnt) {
                        int row = (ntb + ni)*16 + lr + k; row = row > 41 ? 41 : row;
                        bf16x8 bfv = *(const bf16x8*)(p2T + row*128 + ((q ^ (row&15))<<3));
                        acc[ni] = __builtin_amdgcn_mfma_f32_16x16x32_bf16(af, bfv, acc[ni], 0,0,0);
                    }
                }
            }
        }
        #pragma unroll
        for (int ni = 0; ni < 2; ++ni) if (ni < ncnt)
            #pragma unroll
            for (int r = 0; r < 4; ++r) {
                int o = ot*16 + lg*4 + r;
                int p = (ntb + ni)*16 + lr;
                if (p < 35) c3o[o*36 + p] = frelu(acc[ni][r] * g3[o] + b3[o]);
            }
    }
    __syncthreads();

    for (int idx = t; idx < 576; idx += 256) {   // pool3 -> global
        int o = idx / 18, q = idx % 18;
        float v = c3o[o*36 + 2*q];
        if (q > 0) v = fmaxf(v, c3o[o*36 + 2*q - 1]);
        aflatG[(size_t)s*576 + idx] = f2bf(v);
    }
}

// ============ K1b: map2 GEMM (validated r2) ============
__global__ __launch_bounds__(256) void k_map2(const unsigned short* __restrict__ aflatG,
    const unsigned short* __restrict__ m2wbT,
    const float* __restrict__ m2b, const float* __restrict__ m2g, const float* __restrict__ m2bb,
    float* __restrict__ a2)
{
    const int t = threadIdx.x, wv = t>>6, l = t&63, lg = l>>4, lr = l&15;
    const int s0 = blockIdx.x*64;
    f32x4 acc[8] = {};
    for (int ks = 0; ks < 18; ++ks) {
        bf16x8 a = *(const bf16x8*)(aflatG + (size_t)(s0 + wv*16 + lr)*576 + ks*32 + lg*8);
        #pragma unroll
        for (int nt = 0; nt < 8; ++nt) {
            bf16x8 b = *(const bf16x8*)(m2wbT + (size_t)(nt*16 + lr)*576 + ks*32 + lg*8);
            acc[nt] = __builtin_amdgcn_mfma_f32_16x16x32_bf16(a, b, acc[nt], 0,0,0);
        }
    }
    #pragma unroll
    for (int nt = 0; nt < 8; ++nt)
        #pragma unroll
        for (int r = 0; r < 4; ++r) {
            int s2 = s0 + wv*16 + lg*4 + r;
            int j = nt*16 + lr;
            a2[(size_t)s2*128 + j] = (acc[nt][r] + m2b[j]) * m2g[j] + m2bb[j];
        }
}

// ================= K2: build X[b,i,d] from a2 + positional encoding =================
__global__ __launch_bounds__(256) void k_buildx(const float* __restrict__ a2, float* __restrict__ X)
{
    int e = blockIdx.x*256 + threadIdx.x;    // < 524288
    int b = e >> 17;
    int r = e & 131071;
    int i = r >> 7, d = r & 127;
    int row = b*1024 + (d & 7)*128 + (i >> 3);
    int col = (i & 7)*16 + (d >> 3);
    float v = a2[row*128 + col];
    int per = b*1024 + (i & 7)*128 + d;
    int pc  = i >> 3;
    int m = pc >> 1;
    double dv = exp((double)(2*m) * (-9.210340371976184/128.0));  // ln(1e4)
    double ang = (double)per * dv;
    float pe = (pc & 1) ? (float)cos(ang) : (float)sin(ang);
    X[e] = v + pe;
}

// ================= K3: H = X @ gw + gb (f32, validated r2) =================
__global__ __launch_bounds__(256) void k_hmat(const float* __restrict__ X, const float* __restrict__ gw,
                                              const float* __restrict__ gb, float* __restrict__ H)
{
    int e = blockIdx.x*256 + threadIdx.x;
    int srow = e >> 7, j = e & 127;
    const float* xr = X + (size_t)srow*128;
    float acc = gb[j];
    for (int k = 0; k < 128; ++k) acc += xr[k] * gw[k*128 + j];
    H[e] = acc;
}

// ================= K4: S = lrelu(H H^T - 1e8*I), 64x64 tiles (validated r2) =================
__global__ __launch_bounds__(256) void k_scores(const float* __restrict__ H, float* __restrict__ S)
{
    __shared__ __align__(16) float HiT[64*68];
    __shared__ __align__(16) float HjT[64*68];
    const int b = blockIdx.z;
    const int i0 = blockIdx.y * 64, j0 = blockIdx.x * 64;
    const int t = threadIdx.x;
    const int kk = t & 63, ilg = t >> 6;
    const int jg = t & 15, ig = t >> 4;
    float acc[4][4] = {};
    const float* Hb = H + (size_t)b*1024*128;
    for (int k0 = 0; k0 < 128; k0 += 64) {
        __syncthreads();
        #pragma unroll
        for (int m2 = 0; m2 < 16; ++m2) {
            int il = ilg*16 + m2;
            HiT[kk*68 + il] = Hb[(size_t)(i0+il)*128 + k0 + kk];
            HjT[kk*68 + il] = Hb[(size_t)(j0+il)*128 + k0 + kk];
        }
        __syncthreads();
        for (int k = 0; k < 64; ++k) {
            float4 a4 = *(const float4*)&HiT[k*68 + ig*4];
            float4 b4 = *(const float4*)&HjT[k*68 + jg*4];
            float av[4] = {a4.x, a4.y, a4.z, a4.w};
            float bv[4] = {b4.x, b4.y, b4.z, b4.w};
            #pragma unroll
            for (int ii = 0; ii < 4; ++ii)
                #pragma unroll
                for (int jj = 0; jj < 4; ++jj) acc[ii][jj] += av[ii]*bv[jj];
        }
    }
    float* Sb = S + (size_t)b*1024*1024;
    #pragma unroll
    for (int ii = 0; ii < 4; ++ii) {
        int i = i0 + ig*4 + ii;
        float vv[4];
        #pragma unroll
        for (int jj = 0; jj < 4; ++jj) {
            int j = j0 + jg*4 + jj;
            float x = acc[ii][jj];
            if (i == j) x -= 1e8f;
            vv[jj] = lrelu(x);
        }
        *(float4*)&Sb[(size_t)i*1024 + j0 + jg*4] = make_float4(vv[0],vv[1],vv[2],vv[3]);
    }
}

// ================= K5: row softmax in place (validated r2) =================
__global__ __launch_bounds__(256) void k_softmax(float* __restrict__ S)
{
    __shared__ float red[256];
    const int b = blockIdx.y, i = blockIdx.x, t = threadIdx.x;
    float* row = S + (size_t)b*1024*1024 + (size_t)i*1024;
    float4 v = *(const float4*)&row[t*4];
    float mx = fmaxf(fmaxf(v.x,v.y), fmaxf(v.z,v.w));
    red[t] = mx; __syncthreads();
    for (int s2 = 128; s2 > 0; s2 >>= 1) { if (t < s2) red[t] = fmaxf(red[t], red[t+s2]); __syncthreads(); }
    mx = red[0]; __syncthreads();
    float e0 = expf(v.x-mx), e1 = expf(v.y-mx), e2 = expf(v.z-mx), e3 = expf(v.w-mx);
    red[t] = e0+e1+e2+e3; __syncthreads();
    for (int s2 = 128; s2 > 0; s2 >>= 1) { if (t < s2) red[t] += red[t+s2]; __syncthreads(); }
    float inv = 1.f / red[0];
    *(float4*)&row[t*4] = make_float4(e0*inv, e1*inv, e2*inv, e3*inv);
}

// ================= K6: P = (S+I) @ (X*bng+bnb) (validated r2) =================
__global__ __launch_bounds__(256) void k_pv(const float* __restrict__ S, const float* __restrict__ X,
                                            const float* __restrict__ bng, const float* __restrict__ bnb,
                                            float* __restrict__ P)
{
    __shared__ __align__(16) float Sl[16*65];
    __shared__ __align__(16) float Xl[64*132];
    const int b = blockIdx.y, i0 = blockIdx.x*16, t = threadIdx.x;
    const int il = t >> 4, dg = t & 15;
    const int sj = t & 63, sil = t >> 6;
    const int xd = t & 127, xj = t >> 7;
    const float bg = bng[xd], bb = bnb[xd];
    float acc[8] = {};
    const float* Sb = S + (size_t)b*1024*1024;
    const float* Xb = X + (size_t)b*1024*128;
    for (int c = 0; c < 16; ++c) {
        int jb = c*64;
        __syncthreads();
        #pragma unroll
        for (int m2 = 0; m2 < 4; ++m2) {
            int r2 = sil*4 + m2;
            Sl[r2*65 + sj] = Sb[(size_t)(i0+r2)*1024 + jb + sj];
        }
        #pragma unroll
        for (int m2 = 0; m2 < 32; ++m2) {
            int jc = xj + 2*m2;
            Xl[jc*132 + xd] = Xb[(size_t)(jb+jc)*128 + xd] * bg + bb;
        }
        __syncthreads();
        for (int jc = 0; jc < 64; ++jc) {
            float sv = Sl[il*65 + jc];
            float4 x0 = *(const float4*)&Xl[jc*132 + dg*8];
            float4 x1 = *(const float4*)&Xl[jc*132 + dg*8 + 4];
            acc[0] += sv*x0.x; acc[1] += sv*x0.y; acc[2] += sv*x0.z; acc[3] += sv*x0.w;
            acc[4] += sv*x1.x; acc[5] += sv*x1.y; acc[6] += sv*x1.z; acc[7] += sv*x1.w;
        }
    }
    int i = i0 + il;
    const float* xr = Xb + (size_t)i*128 + dg*8;
    float* pr = P + (size_t)(b*1024 + i)*128 + dg*8;
    #pragma unroll
    for (int z = 0; z < 8; ++z) {
        float xv = xr[z] * bng[dg*8+z] + bnb[dg*8+z];
        pr[z] = acc[z] + xv;
    }
}

// ================= K7: O = lrelu(P @ tw + tb) (validated r2) =================
__global__ __launch_bounds__(256) void k_tproj(const float* __restrict__ P, const float* __restrict__ tw,
                                               const float* __restrict__ tb, float* __restrict__ O)
{
    int idx = blockIdx.x*256 + threadIdx.x;   // 4096*64
    int srow = idx >> 6, e = idx & 63;
    const float* pr = P + (size_t)srow*128;
    float acc = tb[e];
    for (int d = 0; d < 128; ++d) acc += pr[d] * tw[d*64 + e];
    O[idx] = lrelu(acc);
}

// ================= K8: fc1 partial sums (validated r2) =================
__global__ __launch_bounds__(256) void k_fc1(const float* __restrict__ O1, const float* __restrict__ O2,
                                             const float* __restrict__ w, float* __restrict__ pbuf)
{
    __shared__ float red[4*512];
    const int t = threadIdx.x;
    const int wv = t >> 6, l = t & 63;
    const int gwid = blockIdx.x*4 + wv;   // 0..2047
    float acc[4][2] = {};
    int base = gwid*64;
    for (int tt = 0; tt < 64; ++tt) {
        int row = base + tt;
        float2 wvv = *(const float2*)&w[(size_t)row*128 + l*2];
        #pragma unroll
        for (int b = 0; b < 4; ++b) {
            float fb = (row < 65536) ? O1[b*65536 + row] : O2[b*65536 + row - 65536];
            acc[b][0] += fb * wvv.x;
            acc[b][1] += fb * wvv.y;
        }
    }
    #pragma unroll
    for (int b = 0; b < 4; ++b) {
        red[wv*512 + b*128 + l*2]   = acc[b][0];
        red[wv*512 + b*128 + l*2+1] = acc[b][1];
    }
    __syncthreads();
    for (int rep = 0; rep < 2; ++rep) {
        int col = rep*256 + t;
        pbuf[(size_t)blockIdx.x*512 + col] = red[col] + red[512+col] + red[1024+col] + red[1536+col];
    }
}

// ============ K8b: parallel reduce of fc1 partials (512 blocks -> 1) ============
__global__ __launch_bounds__(256) void k_red(const float* __restrict__ pbuf, float* __restrict__ pbuf2)
{
    int col = blockIdx.x*8 + (threadIdx.x >> 5);
    int lane = threadIdx.x & 31;
    float acc = 0.f;
    for (int it = 0; it < 16; ++it)
        acc += pbuf[(size_t)(lane + it*32)*512 + col];
    #pragma unroll
    for (int s2 = 16; s2 >= 1; s2 >>= 1) acc += __shfl_xor(acc, s2, 32);
    if (lane == 0) pbuf2[col] = acc;
}

// ============ K9: MLP head (fc1 bias/relu + fc2/fc3/fc4) ============
__global__ __launch_bounds__(256) void k_head2(const float* __restrict__ pbuf2,
    const float* __restrict__ fc1b, const float* __restrict__ fc2w, const float* __restrict__ fc2b,
    const float* __restrict__ fc3w, const float* __restrict__ fc3b,
    const float* __restrict__ fc4w, const float* __restrict__ fc4b,
    float* __restrict__ out)
{
    __shared__ float r1[512], r2[512], r3[256];
    const int t = threadIdx.x;
    for (int rep = 0; rep < 2; ++rep) {
        int idx = rep*256 + t;
        r1[idx] = frelu(pbuf2[idx] + fc1b[idx & 127]);
    }
    __syncthreads();
    for (int rep = 0; rep < 2; ++rep) {
        int idx = rep*256 + t;
        int b = idx >> 7, j = idx & 127;
        float acc = fc2b[j];
        for (int k = 0; k < 128; ++k) acc += r1[b*128+k]*fc2w[k*128+j];
        r2[idx] = frelu(acc);
    }
    __syncthreads();
    {
        int b = t >> 6, e2 = t & 63;
        float acc = fc3b[e2];
        for (int k = 0; k < 128; ++k) acc += r2[b*128+k]*fc3w[k*64+e2];
        r3[t] = frelu(acc);
    }
    __syncthreads();
    if (t < 24) {
        int b = t/6, c = t%6;
        float acc = fc4b[c];
        for (int k = 0; k < 64; ++k) acc += r3[b*64+k]*fc4w[k*6+c];
        out[b*6+c] = acc;
    }
}

extern "C" void kernel_launch(void* const* d_in, const int* in_sizes, int n_in,
                              void* d_out, int out_size, void* d_ws, size_t ws_size,
                              hipStream_t stream)
{
    (void)in_sizes; (void)n_in; (void)out_size; (void)ws_size;
    const float* xenc = (const float*)d_in[0];
    const float* w1   = (const float*)d_in[4];
    const float* g1   = (const float*)d_in[5];
    const float* b1   = (const float*)d_in[6];
    const float* w2   = (const float*)d_in[7];
    const float* g2   = (const float*)d_in[8];
    const float* b2   = (const float*)d_in[9];
    const float* w3   = (const float*)d_in[10];
    const float* g3   = (const float*)d_in[11];
    const float* b3   = (const float*)d_in[12];
    const float* m2w  = (const float*)d_in[13];
    const float* m2b  = (const float*)d_in[14];
    const float* m2g  = (const float*)d_in[15];
    const float* m2bb = (const float*)d_in[16];
    const float* g1w  = (const float*)d_in[17];
    const float* g1b  = (const float*)d_in[18];
    const float* m1g  = (const float*)d_in[19];
    const float* m1b  = (const float*)d_in[20];
    const float* t1w  = (const float*)d_in[21];
    const float* t1b  = (const float*)d_in[22];
    const float* g2w  = (const float*)d_in[23];
    const float* g2bv = (const float*)d_in[24];
    const float* mm2g = (const float*)d_in[25];
    const float* mm2b = (const float*)d_in[26];
    const float* t2w  = (const float*)d_in[27];
    const float* t2b  = (const float*)d_in[28];
    const float* fc1w = (const float*)d_in[29];
    const float* fc1b = (const float*)d_in[30];
    const float* fc2w = (const float*)d_in[31];
    const float* fc2b = (const float*)d_in[32];
    const float* fc3w = (const float*)d_in[33];
    const float* fc3b = (const float*)d_in[34];
    const float* fc4w = (const float*)d_in[35];
    const float* fc4b = (const float*)d_in[36];

    char* ws = (char*)d_ws;
    float* a2   = (float*)(ws);                 // 2 MB
    float* X    = (float*)(ws + (2u<<20));      // 2 MB
    float* H    = (float*)(ws + (4u<<20));      // 2 MB
    float* S    = (float*)(ws + (6u<<20));      // 16 MB
    float* P    = (float*)(ws + (22u<<20));     // 2 MB
    float* O1   = (float*)(ws + (24u<<20));     // 1 MB
    float* O2   = (float*)(ws + (25u<<20));     // 1 MB
    float* pbuf = (float*)(ws + (26u<<20));     // 1 MB
    // transient buffers overlaid on S's region (dead before k_scores writes S)
    unsigned short* aflatG = (unsigned short*)(ws + (6u<<20));             // 4.72 MB
    unsigned short* w2s    = (unsigned short*)(ws + (6u<<20) + 5242880);   // 128 KB
    unsigned short* w3s    = (unsigned short*)(ws + (6u<<20) + 5242880 + 131072);  // 64 KB
    unsigned short* m2wbT  = (unsigned short*)(ws + (6u<<20) + 5242880 + 196608);  // 144 KB
    // pbuf2 also aliases the S region: S is dead after the last k_pv; k_red
    // rewrites pbuf2 before k_head2 reads it on every replay (fixed order).
    float* pbuf2 = (float*)(ws + (6u<<20));     // 2 KB

    k_prep<<<288, 256, 0, stream>>>(w2, w3, m2w, w2s, w3s, m2wbT);
    k_conv<<<4096, 256, 0, stream>>>(xenc, w1,g1,b1, w2s,g2,b2, w3s,g3,b3, aflatG);
    k_map2<<<64, 256, 0, stream>>>(aflatG, m2wbT, m2b, m2g, m2bb, a2);
    k_buildx<<<2048, 256, 0, stream>>>(a2, X);
    // branch 1
    k_hmat   <<<2048, 256, 0, stream>>>(X, g1w, g1b, H);
    k_scores <<<dim3(16,16,4), 256, 0, stream>>>(H, S);
    k_softmax<<<dim3(1024,4), 256, 0, stream>>>(S);
    k_pv     <<<dim3(64,4), 256, 0, stream>>>(S, X, m1g, m1b, P);
    k_tproj  <<<1024, 256, 0, stream>>>(P, t1w, t1b, O1);
    // branch 2
    k_hmat   <<<2048, 256, 0, stream>>>(X, g2w, g2bv, H);
    k_scores <<<dim3(16,16,4), 256, 0, stream>>>(H, S);
    k_softmax<<<dim3(1024,4), 256, 0, stream>>>(S);
    k_pv     <<<dim3(64,4), 256, 0, stream>>>(S, X, mm2g, mm2b, P);
    k_tproj  <<<1024, 256, 0, stream>>>(P, t2w, t2b, O2);
    // head
    k_fc1 <<<512, 256, 0, stream>>>(O1, O2, fc1w, pbuf);
    k_red <<<64, 256, 0, stream>>>(pbuf, pbuf2);
    k_head2<<<1, 256, 0, stream>>>(pbuf2, fc1b, fc2w, fc2b, fc3w, fc3b, fc4w, fc4b, (float*)d_out);
}

// Round 6
// 351.756 us; speedup vs baseline: 4.1919x; 1.0477x over previous
//
#include <hip/hip_runtime.h>
#include <math.h>

#define NEG 0.01f
__device__ __forceinline__ float lrelu(float v){ return v > 0.f ? v : NEG*v; }
__device__ __forceinline__ float frelu(float v){ return v > 0.f ? v : 0.f; }

typedef __attribute__((ext_vector_type(8))) short bf16x8;
typedef __attribute__((ext_vector_type(4))) float f32x4;

__device__ __forceinline__ unsigned short f2bf(float x){
    unsigned int u = __float_as_uint(x);
    unsigned int r = (u + 0x7FFFu + ((u>>16)&1u)) >> 16;
    return (unsigned short)r;
}
__device__ __forceinline__ float bf2f(unsigned short h){
    return __uint_as_float(((unsigned int)h) << 16);
}

// ============ K0: weight repack (frag-ready layouts, bf16) ============
__global__ __launch_bounds__(256) void k_prep(const float* __restrict__ w2, const float* __restrict__ w3,
    const float* __restrict__ m2w,
    unsigned short* __restrict__ w2s, unsigned short* __restrict__ w3s, unsigned short* __restrict__ m2wbT)
{
    int gid = blockIdx.x*256 + threadIdx.x;
    if (gid < 73728) {
        int j = gid / 576, f = gid % 576;
        m2wbT[gid] = f2bf(m2w[f*128 + j]);
    }
    if (gid < 65536) {
        int jj = gid & 7, q = (gid>>3)&3, o = (gid>>5)&127, ks = (gid>>12)&1, k = gid>>13;
        int c = ks*32 + q*8 + jj;
        w2s[gid] = f2bf(w2[o*512 + c*8 + k]);
    }
    if (gid < 32768) {
        int jj = gid & 7, q = (gid>>3)&3, o = (gid>>5)&31, ks = (gid>>10)&3, k = gid>>12;
        int c = ks*32 + q*8 + jj;
        w3s[gid] = f2bf(w3[o*1024 + c*8 + k]);
    }
}

// ============ K1: fused conv stack, MFMA for conv2/conv3 (validated r2) ============
__global__ __launch_bounds__(256) void k_conv(
    const float* __restrict__ xenc,
    const float* __restrict__ w1, const float* __restrict__ g1, const float* __restrict__ b1,
    const unsigned short* __restrict__ w2s, const float* __restrict__ g2, const float* __restrict__ b2,
    const unsigned short* __restrict__ w3s, const float* __restrict__ g3, const float* __restrict__ b3,
    unsigned short* __restrict__ aflatG)
{
    __shared__ __align__(16) unsigned char smraw[38464];
    float* sigp = (float*)smraw;
    unsigned short* p1T = (unsigned short*)(smraw + 576);
    unsigned short* p2T = (unsigned short*)(smraw + 10304);
    unsigned short* c2o = (unsigned short*)(smraw + 21056);
    float* c3o = (float*)(smraw + 21056);

    const int t = threadIdx.x;
    const int s = blockIdx.x;

    {
        unsigned int* zz = (unsigned int*)(smraw + 576);
        for (int i = t; i < 5120; i += 256) zz[i] = 0u;
        if (t < 136) sigp[t] = 0.f;
    }
    __syncthreads();
    if (t < 128) sigp[4 + t] = xenc[(size_t)s*128 + t];
    __syncthreads();

    {   // conv1 f32 + bn + relu + pool -> p1T (bf16, swizzled)
        const int c = t & 63, qg = t >> 6;
        float wr[8];
        #pragma unroll
        for (int k = 0; k < 8; ++k) wr[k] = w1[c*8 + k];
        const float g = g1[c], b = b1[c];
        for (int m = 0; m < 17; ++m) {
            int q = qg + 4*m;
            if (q < 65) {
                float s1 = 0.f;
                #pragma unroll
                for (int k = 0; k < 8; ++k) s1 += sigp[2*q + k] * wr[k];
                float v = frelu(s1*g + b);
                if (q > 0) {
                    float s0 = 0.f;
                    #pragma unroll
                    for (int k = 0; k < 8; ++k) s0 += sigp[2*q - 1 + k] * wr[k];
                    v = fmaxf(v, frelu(s0*g + b));
                }
                int row = q + 4;
                p1T[row*64 + (((c>>3) ^ (row&7))<<3) + (c&7)] = f2bf(v);
            }
        }
    }
    __syncthreads();

    {   // conv2 MFMA
        const int wv = t >> 6, l = t & 63, lg = l >> 4, lr = l & 15;
        f32x4 acc[2][5] = {};
        for (int k = 0; k < 8; ++k) {
            for (int ks = 0; ks < 2; ++ks) {
                bf16x8 af[2];
                #pragma unroll
                for (int oi = 0; oi < 2; ++oi) {
                    int o = (wv*2 + oi)*16 + lr;
                    af[oi] = *(const bf16x8*)(w2s + ((((k*2 + ks)*128 + o)*4 + lg)<<3));
                }
                #pragma unroll
                for (int nt = 0; nt < 5; ++nt) {
                    int row = nt*16 + lr + k; row = row > 75 ? 75 : row;
                    int q = ks*4 + lg;
                    bf16x8 bfv = *(const bf16x8*)(p1T + row*64 + ((q ^ (row&7))<<3));
                    acc[0][nt] = __builtin_amdgcn_mfma_f32_16x16x32_bf16(af[0], bfv, acc[0][nt], 0,0,0);
                    acc[1][nt] = __builtin_amdgcn_mfma_f32_16x16x32_bf16(af[1], bfv, acc[1][nt], 0,0,0);
                }
            }
        }
        #pragma unroll
        for (int oi = 0; oi < 2; ++oi)
            #pragma unroll
            for (int nt = 0; nt < 5; ++nt)
                #pragma unroll
                for (int r = 0; r < 4; ++r) {
                    int o = (wv*2 + oi)*16 + lg*4 + r;
                    int p = nt*16 + lr;
                    if (p < 66) c2o[o*68 + p] = f2bf(frelu(acc[oi][nt][r] * g2[o] + b2[o]));
                }
    }
    __syncthreads();

    for (int idx = t; idx < 4352; idx += 256) {   // pool2
        int o = idx & 127, q = idx >> 7;
        unsigned short v = (q <= 32) ? c2o[o*68 + 2*q] : (unsigned short)0;
        if (q > 0) { unsigned short v2 = c2o[o*68 + 2*q - 1]; v = (v2 > v) ? v2 : v; }
        int row = q + 4;
        p2T[row*128 + (((o>>3) ^ (row&15))<<3) + (o&7)] = v;
    }
    __syncthreads();

    {   // conv3 MFMA
        const int wv = t >> 6, l = t & 63, lg = l >> 4, lr = l & 15;
        const int ot = wv & 1, ntb = (wv >> 1) * 2;
        const int ncnt = (wv < 2) ? 2 : 1;
        f32x4 acc[2] = {};
        for (int k = 0; k < 8; ++k) {
            for (int ks = 0; ks < 4; ++ks) {
                int o = ot*16 + lr;
                bf16x8 af = *(const bf16x8*)(w3s + ((((k*4 + ks)*32 + o)*4 + lg)<<3));
                int q = ks*4 + lg;
                #pragma unroll
                for (int ni = 0; ni < 2; ++ni) {
                    if (ni < ncnt) {
                        int row = (ntb + ni)*16 + lr + k; row = row > 41 ? 41 : row;
                        bf16x8 bfv = *(const bf16x8*)(p2T + row*128 + ((q ^ (row&15))<<3));
                        acc[ni] = __builtin_amdgcn_mfma_f32_16x16x32_bf16(af, bfv, acc[ni], 0,0,0);
                    }
                }
            }
        }
        #pragma unroll
        for (int ni = 0; ni < 2; ++ni) if (ni < ncnt)
            #pragma unroll
            for (int r = 0; r < 4; ++r) {
                int o = ot*16 + lg*4 + r;
                int p = (ntb + ni)*16 + lr;
                if (p < 35) c3o[o*36 + p] = frelu(acc[ni][r] * g3[o] + b3[o]);
            }
    }
    __syncthreads();

    for (int idx = t; idx < 576; idx += 256) {   // pool3 -> global
        int o = idx / 18, q = idx % 18;
        float v = c3o[o*36 + 2*q];
        if (q > 0) v = fmaxf(v, c3o[o*36 + 2*q - 1]);
        aflatG[(size_t)s*576 + idx] = f2bf(v);
    }
}

// ============ K1b: map2 GEMM (validated r2) ============
__global__ __launch_bounds__(256) void k_map2(const unsigned short* __restrict__ aflatG,
    const unsigned short* __restrict__ m2wbT,
    const float* __restrict__ m2b, const float* __restrict__ m2g, const float* __restrict__ m2bb,
    float* __restrict__ a2)
{
    const int t = threadIdx.x, wv = t>>6, l = t&63, lg = l>>4, lr = l&15;
    const int s0 = blockIdx.x*64;
    f32x4 acc[8] = {};
    for (int ks = 0; ks < 18; ++ks) {
        bf16x8 a = *(const bf16x8*)(aflatG + (size_t)(s0 + wv*16 + lr)*576 + ks*32 + lg*8);
        #pragma unroll
        for (int nt = 0; nt < 8; ++nt) {
            bf16x8 b = *(const bf16x8*)(m2wbT + (size_t)(nt*16 + lr)*576 + ks*32 + lg*8);
            acc[nt] = __builtin_amdgcn_mfma_f32_16x16x32_bf16(a, b, acc[nt], 0,0,0);
        }
    }
    #pragma unroll
    for (int nt = 0; nt < 8; ++nt)
        #pragma unroll
        for (int r = 0; r < 4; ++r) {
            int s2 = s0 + wv*16 + lg*4 + r;
            int j = nt*16 + lr;
            a2[(size_t)s2*128 + j] = (acc[nt][r] + m2b[j]) * m2g[j] + m2bb[j];
        }
}

// ================= K2: build X[b,i,d] from a2 + positional encoding =================
__global__ __launch_bounds__(256) void k_buildx(const float* __restrict__ a2, float* __restrict__ X)
{
    int e = blockIdx.x*256 + threadIdx.x;    // < 524288
    int b = e >> 17;
    int r = e & 131071;
    int i = r >> 7, d = r & 127;
    int row = b*1024 + (d & 7)*128 + (i >> 3);
    int col = (i & 7)*16 + (d >> 3);
    float v = a2[row*128 + col];
    int per = b*1024 + (i & 7)*128 + d;
    int pc  = i >> 3;
    int m = pc >> 1;
    double dv = exp((double)(2*m) * (-9.210340371976184/128.0));  // ln(1e4)
    double ang = (double)per * dv;
    float pe = (pc & 1) ? (float)cos(ang) : (float)sin(ang);
    X[e] = v + pe;
}

// ===== K3: H = X @ gw + gb (f32 math, validated) -> bf16 hi/lo split output =====
__global__ __launch_bounds__(256) void k_hmat(const float* __restrict__ X, const float* __restrict__ gw,
                                              const float* __restrict__ gb,
                                              unsigned short* __restrict__ Hbhi,
                                              unsigned short* __restrict__ Hblo)
{
    int e = blockIdx.x*256 + threadIdx.x;
    int srow = e >> 7, j = e & 127;
    const float* xr = X + (size_t)srow*128;
    float acc = gb[j];
    for (int k = 0; k < 128; ++k) acc += xr[k] * gw[k*128 + j];
    unsigned short hh = f2bf(acc);
    Hbhi[e] = hh;
    Hblo[e] = f2bf(acc - bf2f(hh));
}

// ===== K4: S = lrelu(H H^T - 1e8*I) via bf16 hi/lo MFMA, 64x64 tiles =====
// Fragment convention IDENTICAL to validated k_map2: A lane-row = strip+(l&15),
// B lane-col = tile+(l&15), k = kc*32+(l>>4)*8, out row=(l>>4)*4+r, col=(l&15).
__global__ __launch_bounds__(256) void k_scores(
    const unsigned short* __restrict__ Hbhi, const unsigned short* __restrict__ Hblo,
    float* __restrict__ S)
{
    // per k-half staging: 4 arrays [64 rows][64 k] bf16, granule-XOR swizzled
    __shared__ __align__(16) unsigned short HiH[64*64];
    __shared__ __align__(16) unsigned short HiL[64*64];
    __shared__ __align__(16) unsigned short HjH[64*64];
    __shared__ __align__(16) unsigned short HjL[64*64];
    const int b = blockIdx.z;
    const int i0 = blockIdx.y * 64, j0 = blockIdx.x * 64;
    const int t = threadIdx.x;
    const int w = t >> 6, l = t & 63, lr = l & 15, h = l >> 4;
    const size_t hb = (size_t)b * 1024 * 128;

    f32x4 acc[4] = {};
    for (int kh = 0; kh < 2; ++kh) {
        __syncthreads();   // protect previous half's LDS reads
        #pragma unroll
        for (int it = 0; it < 4; ++it) {
            int g = it*256 + t;          // 0..1023 granule-pairs
            int mat = g >> 9;            // 0: Hi, 1: Hj
            int gg = g & 511;
            int row = gg >> 3, ch = gg & 7;
            int base0 = mat ? j0 : i0;
            size_t src = hb + (size_t)(base0 + row)*128 + kh*64 + ch*8;
            uint4 vh = *(const uint4*)(Hbhi + src);
            uint4 vl = *(const uint4*)(Hblo + src);
            int sw = ch ^ (row & 7);
            unsigned short* dh = (mat ? HjH : HiH) + row*64 + sw*8;
            unsigned short* dl = (mat ? HjL : HiL) + row*64 + sw*8;
            *(uint4*)dh = vh;
            *(uint4*)dl = vl;
        }
        __syncthreads();
        #pragma unroll
        for (int kc = 0; kc < 2; ++kc) {
            int swA = (((kc*4 + h) ^ (lr & 7)) << 3);
            bf16x8 ah = *(const bf16x8*)&HiH[(w*16 + lr)*64 + swA];
            bf16x8 al = *(const bf16x8*)&HiL[(w*16 + lr)*64 + swA];
            #pragma unroll
            for (int jt = 0; jt < 4; ++jt) {
                bf16x8 bh = *(const bf16x8*)&HjH[(jt*16 + lr)*64 + swA];
                bf16x8 bl = *(const bf16x8*)&HjL[(jt*16 + lr)*64 + swA];
                acc[jt] = __builtin_amdgcn_mfma_f32_16x16x32_bf16(ah, bh, acc[jt], 0,0,0);
                acc[jt] = __builtin_amdgcn_mfma_f32_16x16x32_bf16(ah, bl, acc[jt], 0,0,0);
                acc[jt] = __builtin_amdgcn_mfma_f32_16x16x32_bf16(al, bh, acc[jt], 0,0,0);
            }
        }
    }
    float* Sb = S + (size_t)b*1024*1024;
    #pragma unroll
    for (int jt = 0; jt < 4; ++jt) {
        #pragma unroll
        for (int r = 0; r < 4; ++r) {
            int i = i0 + w*16 + h*4 + r;
            int j = j0 + jt*16 + lr;
            float x = acc[jt][r];
            if (i == j) x -= 1e8f;
            Sb[(size_t)i*1024 + j] = lrelu(x);
        }
    }
}

// ================= K5: row softmax in place (validated r2) =================
__global__ __launch_bounds__(256) void k_softmax(float* __restrict__ S)
{
    __shared__ float red[256];
    const int b = blockIdx.y, i = blockIdx.x, t = threadIdx.x;
    float* row = S + (size_t)b*1024*1024 + (size_t)i*1024;
    float4 v = *(const float4*)&row[t*4];
    float mx = fmaxf(fmaxf(v.x,v.y), fmaxf(v.z,v.w));
    red[t] = mx; __syncthreads();
    for (int s2 = 128; s2 > 0; s2 >>= 1) { if (t < s2) red[t] = fmaxf(red[t], red[t+s2]); __syncthreads(); }
    mx = red[0]; __syncthreads();
    float e0 = expf(v.x-mx), e1 = expf(v.y-mx), e2 = expf(v.z-mx), e3 = expf(v.w-mx);
    red[t] = e0+e1+e2+e3; __syncthreads();
    for (int s2 = 128; s2 > 0; s2 >>= 1) { if (t < s2) red[t] += red[t+s2]; __syncthreads(); }
    float inv = 1.f / red[0];
    *(float4*)&row[t*4] = make_float4(e0*inv, e1*inv, e2*inv, e3*inv);
}

// ================= K6: P = (S+I) @ (X*bng+bnb) (validated r2) =================
__global__ __launch_bounds__(256) void k_pv(const float* __restrict__ S, const float* __restrict__ X,
                                            const float* __restrict__ bng, const float* __restrict__ bnb,
                                            float* __restrict__ P)
{
    __shared__ __align__(16) float Sl[16*65];
    __shared__ __align__(16) float Xl[64*132];
    const int b = blockIdx.y, i0 = blockIdx.x*16, t = threadIdx.x;
    const int il = t >> 4, dg = t & 15;
    const int sj = t & 63, sil = t >> 6;
    const int xd = t & 127, xj = t >> 7;
    const float bg = bng[xd], bb = bnb[xd];
    float acc[8] = {};
    const float* Sb = S + (size_t)b*1024*1024;
    const float* Xb = X + (size_t)b*1024*128;
    for (int c = 0; c < 16; ++c) {
        int jb = c*64;
        __syncthreads();
        #pragma unroll
        for (int m2 = 0; m2 < 4; ++m2) {
            int r2 = sil*4 + m2;
            Sl[r2*65 + sj] = Sb[(size_t)(i0+r2)*1024 + jb + sj];
        }
        #pragma unroll
        for (int m2 = 0; m2 < 32; ++m2) {
            int jc = xj + 2*m2;
            Xl[jc*132 + xd] = Xb[(size_t)(jb+jc)*128 + xd] * bg + bb;
        }
        __syncthreads();
        for (int jc = 0; jc < 64; ++jc) {
            float sv = Sl[il*65 + jc];
            float4 x0 = *(const float4*)&Xl[jc*132 + dg*8];
            float4 x1 = *(const float4*)&Xl[jc*132 + dg*8 + 4];
            acc[0] += sv*x0.x; acc[1] += sv*x0.y; acc[2] += sv*x0.z; acc[3] += sv*x0.w;
            acc[4] += sv*x1.x; acc[5] += sv*x1.y; acc[6] += sv*x1.z; acc[7] += sv*x1.w;
        }
    }
    int i = i0 + il;
    const float* xr = Xb + (size_t)i*128 + dg*8;
    float* pr = P + (size_t)(b*1024 + i)*128 + dg*8;
    #pragma unroll
    for (int z = 0; z < 8; ++z) {
        float xv = xr[z] * bng[dg*8+z] + bnb[dg*8+z];
        pr[z] = acc[z] + xv;
    }
}

// ================= K7: O = lrelu(P @ tw + tb) (validated r2) =================
__global__ __launch_bounds__(256) void k_tproj(const float* __restrict__ P, const float* __restrict__ tw,
                                               const float* __restrict__ tb, float* __restrict__ O)
{
    int idx = blockIdx.x*256 + threadIdx.x;   // 4096*64
    int srow = idx >> 6, e = idx & 63;
    const float* pr = P + (size_t)srow*128;
    float acc = tb[e];
    for (int d = 0; d < 128; ++d) acc += pr[d] * tw[d*64 + e];
    O[idx] = lrelu(acc);
}

// ================= K8: fc1 partial sums (validated r2) =================
__global__ __launch_bounds__(256) void k_fc1(const float* __restrict__ O1, const float* __restrict__ O2,
                                             const float* __restrict__ w, float* __restrict__ pbuf)
{
    __shared__ float red[4*512];
    const int t = threadIdx.x;
    const int wv = t >> 6, l = t & 63;
    const int gwid = blockIdx.x*4 + wv;   // 0..2047
    float acc[4][2] = {};
    int base = gwid*64;
    for (int tt = 0; tt < 64; ++tt) {
        int row = base + tt;
        float2 wvv = *(const float2*)&w[(size_t)row*128 + l*2];
        #pragma unroll
        for (int b = 0; b < 4; ++b) {
            float fb = (row < 65536) ? O1[b*65536 + row] : O2[b*65536 + row - 65536];
            acc[b][0] += fb * wvv.x;
            acc[b][1] += fb * wvv.y;
        }
    }
    #pragma unroll
    for (int b = 0; b < 4; ++b) {
        red[wv*512 + b*128 + l*2]   = acc[b][0];
        red[wv*512 + b*128 + l*2+1] = acc[b][1];
    }
    __syncthreads();
    for (int rep = 0; rep < 2; ++rep) {
        int col = rep*256 + t;
        pbuf[(size_t)blockIdx.x*512 + col] = red[col] + red[512+col] + red[1024+col] + red[1536+col];
    }
}

// ============ K8b: parallel reduce of fc1 partials (512 blocks -> 1) ============
__global__ __launch_bounds__(256) void k_red(const float* __restrict__ pbuf, float* __restrict__ pbuf2)
{
    int col = blockIdx.x*8 + (threadIdx.x >> 5);
    int lane = threadIdx.x & 31;
    float acc = 0.f;
    for (int it = 0; it < 16; ++it)
        acc += pbuf[(size_t)(lane + it*32)*512 + col];
    #pragma unroll
    for (int s2 = 16; s2 >= 1; s2 >>= 1) acc += __shfl_xor(acc, s2, 32);
    if (lane == 0) pbuf2[col] = acc;
}

// ============ K9: MLP head (fc1 bias/relu + fc2/fc3/fc4) ============
__global__ __launch_bounds__(256) void k_head2(const float* __restrict__ pbuf2,
    const float* __restrict__ fc1b, const float* __restrict__ fc2w, const float* __restrict__ fc2b,
    const float* __restrict__ fc3w, const float* __restrict__ fc3b,
    const float* __restrict__ fc4w, const float* __restrict__ fc4b,
    float* __restrict__ out)
{
    __shared__ float r1[512], r2[512], r3[256];
    const int t = threadIdx.x;
    for (int rep = 0; rep < 2; ++rep) {
        int idx = rep*256 + t;
        r1[idx] = frelu(pbuf2[idx] + fc1b[idx & 127]);
    }
    __syncthreads();
    for (int rep = 0; rep < 2; ++rep) {
        int idx = rep*256 + t;
        int b = idx >> 7, j = idx & 127;
        float acc = fc2b[j];
        for (int k = 0; k < 128; ++k) acc += r1[b*128+k]*fc2w[k*128+j];
        r2[idx] = frelu(acc);
    }
    __syncthreads();
    {
        int b = t >> 6, e2 = t & 63;
        float acc = fc3b[e2];
        for (int k = 0; k < 128; ++k) acc += r2[b*128+k]*fc3w[k*64+e2];
        r3[t] = frelu(acc);
    }
    __syncthreads();
    if (t < 24) {
        int b = t/6, c = t%6;
        float acc = fc4b[c];
        for (int k = 0; k < 64; ++k) acc += r3[b*64+k]*fc4w[k*6+c];
        out[b*6+c] = acc;
    }
}

extern "C" void kernel_launch(void* const* d_in, const int* in_sizes, int n_in,
                              void* d_out, int out_size, void* d_ws, size_t ws_size,
                              hipStream_t stream)
{
    (void)in_sizes; (void)n_in; (void)out_size; (void)ws_size;
    const float* xenc = (const float*)d_in[0];
    const float* w1   = (const float*)d_in[4];
    const float* g1   = (const float*)d_in[5];
    const float* b1   = (const float*)d_in[6];
    const float* w2   = (const float*)d_in[7];
    const float* g2   = (const float*)d_in[8];
    const float* b2   = (const float*)d_in[9];
    const float* w3   = (const float*)d_in[10];
    const float* g3   = (const float*)d_in[11];
    const float* b3   = (const float*)d_in[12];
    const float* m2w  = (const float*)d_in[13];
    const float* m2b  = (const float*)d_in[14];
    const float* m2g  = (const float*)d_in[15];
    const float* m2bb = (const float*)d_in[16];
    const float* g1w  = (const float*)d_in[17];
    const float* g1b  = (const float*)d_in[18];
    const float* m1g  = (const float*)d_in[19];
    const float* m1b  = (const float*)d_in[20];
    const float* t1w  = (const float*)d_in[21];
    const float* t1b  = (const float*)d_in[22];
    const float* g2w  = (const float*)d_in[23];
    const float* g2bv = (const float*)d_in[24];
    const float* mm2g = (const float*)d_in[25];
    const float* mm2b = (const float*)d_in[26];
    const float* t2w  = (const float*)d_in[27];
    const float* t2b  = (const float*)d_in[28];
    const float* fc1w = (const float*)d_in[29];
    const float* fc1b = (const float*)d_in[30];
    const float* fc2w = (const float*)d_in[31];
    const float* fc2b = (const float*)d_in[32];
    const float* fc3w = (const float*)d_in[33];
    const float* fc3b = (const float*)d_in[34];
    const float* fc4w = (const float*)d_in[35];
    const float* fc4b = (const float*)d_in[36];

    char* ws = (char*)d_ws;
    float* a2   = (float*)(ws);                 // 2 MB
    float* X    = (float*)(ws + (2u<<20));      // 2 MB
    unsigned short* Hbhi = (unsigned short*)(ws + (4u<<20)); // 1 MB (replaces f32 H)
    unsigned short* Hblo = (unsigned short*)(ws + (5u<<20)); // 1 MB
    float* S    = (float*)(ws + (6u<<20));      // 16 MB
    float* P    = (float*)(ws + (22u<<20));     // 2 MB
    float* O1   = (float*)(ws + (24u<<20));     // 1 MB
    float* O2   = (float*)(ws + (25u<<20));     // 1 MB
    float* pbuf = (float*)(ws + (26u<<20));     // 1 MB
    // transient buffers overlaid on S's region (dead before k_scores writes S)
    unsigned short* aflatG = (unsigned short*)(ws + (6u<<20));             // 4.72 MB
    unsigned short* w2s    = (unsigned short*)(ws + (6u<<20) + 5242880);   // 128 KB
    unsigned short* w3s    = (unsigned short*)(ws + (6u<<20) + 5242880 + 131072);  // 64 KB
    unsigned short* m2wbT  = (unsigned short*)(ws + (6u<<20) + 5242880 + 196608);  // 144 KB
    // pbuf2 aliases the S region (S dead after last k_pv; rewritten every replay)
    float* pbuf2 = (float*)(ws + (6u<<20));     // 2 KB

    k_prep<<<288, 256, 0, stream>>>(w2, w3, m2w, w2s, w3s, m2wbT);
    k_conv<<<4096, 256, 0, stream>>>(xenc, w1,g1,b1, w2s,g2,b2, w3s,g3,b3, aflatG);
    k_map2<<<64, 256, 0, stream>>>(aflatG, m2wbT, m2b, m2g, m2bb, a2);
    k_buildx<<<2048, 256, 0, stream>>>(a2, X);
    // branch 1
    k_hmat   <<<2048, 256, 0, stream>>>(X, g1w, g1b, Hbhi, Hblo);
    k_scores <<<dim3(16,16,4), 256, 0, stream>>>(Hbhi, Hblo, S);
    k_softmax<<<dim3(1024,4), 256, 0, stream>>>(S);
    k_pv     <<<dim3(64,4), 256, 0, stream>>>(S, X, m1g, m1b, P);
    k_tproj  <<<1024, 256, 0, stream>>>(P, t1w, t1b, O1);
    // branch 2
    k_hmat   <<<2048, 256, 0, stream>>>(X, g2w, g2bv, Hbhi, Hblo);
    k_scores <<<dim3(16,16,4), 256, 0, stream>>>(Hbhi, Hblo, S);
    k_softmax<<<dim3(1024,4), 256, 0, stream>>>(S);
    k_pv     <<<dim3(64,4), 256, 0, stream>>>(S, X, mm2g, mm2b, P);
    k_tproj  <<<1024, 256, 0, stream>>>(P, t2w, t2b, O2);
    // head
    k_fc1 <<<512, 256, 0, stream>>>(O1, O2, fc1w, pbuf);
    k_red <<<64, 256, 0, stream>>>(pbuf, pbuf2);
    k_head2<<<1, 256, 0, stream>>>(pbuf2, fc1b, fc2w, fc2b, fc3w, fc3b, fc4w, fc4b, (float*)d_out);
}